// Round 11
// baseline (509.627 us; speedup 1.0000x reference)
//
#include <hip/hip_runtime.h>
#include <math.h>

#define NN 100000
#define EE 1600000
#define BB 64
#define FF 16
#define HH 128
#define GG 8
#define K0 19
#define BN_EPS 1e-5f
#define BSHIFT 8
#define BNODES 256
#define NBINS 391          // ceil(NN/256)
#define BCAP 8192
#define ACH 2048           // edges per phase-A block
#define NB_WP 320          // (5*HH*HH+255)/256
#define NB_X0 12500        // NN*32/256
#define STSLOT 8           // atomic-stat shadow copies

typedef short bf16x8 __attribute__((ext_vector_type(8)));
typedef float f32x4 __attribute__((ext_vector_type(4)));

__device__ __forceinline__ float elu01f(float v) {
    return v > 0.f ? v : 0.1f * (__expf(v) - 1.f);
}

__device__ __forceinline__ unsigned f2bfu(float f) {
    unsigned u = __float_as_uint(f);
    unsigned r = u + 0x7FFFu + ((u >> 16) & 1u);
    return r >> 16;
}
__device__ __forceinline__ short f2bf(float f) { return (short)f2bfu(f); }
__device__ __forceinline__ float bfu2f(unsigned short b) {
    return __uint_as_float(((unsigned)b) << 16);
}
__device__ __forceinline__ float bflo(unsigned u) { return __uint_as_float(u << 16); }
__device__ __forceinline__ float bfhi(unsigned u) { return __uint_as_float(u & 0xffff0000u); }

// monotonic float<->uint encoding: order-preserving, 0 encodes -inf sentinel
__device__ __forceinline__ unsigned fenc(float f) {
    unsigned u = __float_as_uint(f);
    return (u & 0x80000000u) ? ~u : (u | 0x80000000u);
}
__device__ __forceinline__ float fdec(unsigned e) {
    unsigned u = (e & 0x80000000u) ? (e & 0x7FFFFFFFu) : ~e;
    return __uint_as_float(u);
}

// ---------------- CSR build: 2-phase LDS counting sort (512 threads) ----------------
__global__ __launch_bounds__(512) void k_binA(const int* __restrict__ esrc, const int* __restrict__ edst,
                                              int* __restrict__ bincnt, uint2* __restrict__ binbuf) {
    __shared__ int hist[NBINS];
    __shared__ int gbase[NBINS];
    __shared__ int cur[NBINS];
    __shared__ int sc[512];
    __shared__ uint2 ebuf[ACH];
    __shared__ uint2 sorted[ACH];
    int tid = threadIdx.x;
    int e0 = blockIdx.x * ACH;
    int n = min(ACH, EE - e0);
    if (tid < NBINS) hist[tid] = 0;
    __syncthreads();
    for (int i = tid; i < n; i += 512) {
        int s = esrc[e0 + i];
        int d = edst[e0 + i];
        ebuf[i] = make_uint2((unsigned)s, (unsigned)d);
        atomicAdd(&hist[d >> BSHIFT], 1);
    }
    __syncthreads();
    sc[tid] = (tid < NBINS) ? hist[tid] : 0;
    __syncthreads();
    for (int off = 1; off < 512; off <<= 1) {
        int v = (tid >= off) ? sc[tid - off] : 0;
        __syncthreads();
        sc[tid] += v;
        __syncthreads();
    }
    if (tid < NBINS) {
        int c = hist[tid];
        gbase[tid] = (c > 0) ? atomicAdd(&bincnt[tid], c) : 0;
        cur[tid] = (tid > 0) ? sc[tid - 1] : 0;
    }
    __syncthreads();
    for (int i = tid; i < n; i += 512) {
        uint2 e = ebuf[i];
        int b = (int)(e.y >> BSHIFT);
        int pos = atomicAdd(&cur[b], 1);
        sorted[pos] = e;
    }
    __syncthreads();
    for (int i = tid; i < n; i += 512) {
        uint2 e = sorted[i];
        int b = (int)(e.y >> BSHIFT);
        int ls = (b > 0) ? sc[b - 1] : 0;
        int gpos = gbase[b] + (i - ls);
        binbuf[(size_t)b * BCAP + gpos] = e;
    }
}

// phase B: per-bin counting sort; block computes its own global base from bincnt (512 threads)
__global__ __launch_bounds__(512) void k_binB(const uint2* __restrict__ binbuf, const int* __restrict__ bincnt,
                                              int* __restrict__ rp, int* __restrict__ srcs) {
    __shared__ int hist[BNODES];
    __shared__ int scx[BNODES];
    __shared__ int scur[BNODES];
    __shared__ int rsum[512];
    __shared__ int sbuf[BCAP];
    int b = blockIdx.x;
    int n = bincnt[b];
    int tid = threadIdx.x;
    // base = sum bincnt[0..b-1]
    rsum[tid] = (tid < b) ? bincnt[tid] : 0;
    if (tid < BNODES) hist[tid] = 0;
    __syncthreads();
    for (int off = 256; off > 0; off >>= 1) {
        if (tid < off) rsum[tid] += rsum[tid + off];
        __syncthreads();
    }
    int base = rsum[0];
    const uint2* eb = binbuf + (size_t)b * BCAP;
    for (int i = tid; i < n; i += 512)
        atomicAdd(&hist[eb[i].y & (BNODES - 1)], 1);
    __syncthreads();
    if (tid < BNODES) scx[tid] = hist[tid];
    __syncthreads();
    for (int off = 1; off < BNODES; off <<= 1) {
        int vv = (tid >= off && tid < BNODES) ? scx[tid - off] : 0;
        __syncthreads();
        if (tid < BNODES) scx[tid] += vv;
        __syncthreads();
    }
    if (tid < BNODES) {
        int excl = (tid > 0) ? scx[tid - 1] : 0;
        int node = (b << BSHIFT) + tid;
        if (node < NN) rp[node] = base + excl;
        scur[tid] = excl;
    }
    if (b == NBINS - 1 && tid == 0) rp[NN] = EE;
    __syncthreads();
    for (int i = tid; i < n; i += 512) {
        uint2 e = eb[i];
        int pos = atomicAdd(&scur[e.y & (BNODES - 1)], 1);
        sbuf[pos] = (int)e.x;
    }
    __syncthreads();
    for (int i = tid; i < n; i += 512) srcs[base + i] = sbuf[i];
}

// ---------------- merged prep: weight transpose + x0 feature build + gptr search ----------------
__global__ __launch_bounds__(256) void k_prep(const float* __restrict__ w2_0, const float* __restrict__ w1_r,
                                              const float* __restrict__ w2_r, short* __restrict__ wt,
                                              const float* __restrict__ h0, const float* __restrict__ coord,
                                              unsigned short* __restrict__ x0,
                                              const int* __restrict__ batch, int* __restrict__ gptr) {
    int b = blockIdx.x;
    int tid = threadIdx.x;
    if (b == 0 && tid <= BB) {
        int t = tid;
        int lo = 0, hi = NN;
        while (lo < hi) { int mid = (lo + hi) >> 1; if (batch[mid] < t) lo = mid + 1; else hi = mid; }
        gptr[t] = lo;
    }
    if (b < NB_WP) {
        int t = b * 256 + tid;
        if (t >= 5 * HH * HH) return;
        int m = t >> 14;
        int rem = t & 16383;
        int col = rem >> 7;
        int k = rem & 127;
        const float* src = (m == 0) ? w2_0 : (m <= 2 ? w1_r + (size_t)(m - 1) * HH * HH
                                                     : w2_r + (size_t)(m - 3) * HH * HH);
        wt[t] = f2bf(src[k * HH + col]);
    } else {
        int i = (b - NB_WP) * 256 + tid;
        if (i >= NN * 32) return;
        int node = i >> 5, k = i & 31;
        float v = 0.f;
        if (k < FF) v = h0[node * FF + k];
        else if (k < K0) v = coord[node * 3 + (k - FF)];
        x0[i] = (unsigned short)f2bfu(v);
    }
}

// ---------------- layer-0 aggregation: wave per node, 16 edges in flight, f32 out ----------------
__global__ __launch_bounds__(256) void k_agg_small(const uint4* __restrict__ x, const int* __restrict__ rp,
                                                   const int* __restrict__ srcs, float* __restrict__ y) {
    int w = (blockIdx.x * 256 + threadIdx.x) >> 6;
    int lane = threadIdx.x & 63;
    if (w >= NN) return;
    int e = lane >> 2, q = lane & 3;
    int beg = rp[w], end = rp[w + 1];
    float acc[8];
    {   // self row on e==0 lanes
        if (e == 0) {
            uint4 u = x[(size_t)w * 4 + q];
            acc[0] = bflo(u.x); acc[1] = bfhi(u.x);
            acc[2] = bflo(u.y); acc[3] = bfhi(u.y);
            acc[4] = bflo(u.z); acc[5] = bfhi(u.z);
            acc[6] = bflo(u.w); acc[7] = bfhi(u.w);
        } else {
            #pragma unroll
            for (int j = 0; j < 8; j++) acc[j] = 0.f;
        }
    }
    for (int p = beg; p < end; p += 16) {
        int rem = end - p;
        bool act = e < rem;
        int sn = act ? srcs[p + e] : 0;
        uint4 u = x[(size_t)sn * 4 + q];
        float m = act ? 1.f : 0.f;
        acc[0] = fmaf(m, bflo(u.x), acc[0]); acc[1] = fmaf(m, bfhi(u.x), acc[1]);
        acc[2] = fmaf(m, bflo(u.y), acc[2]); acc[3] = fmaf(m, bfhi(u.y), acc[3]);
        acc[4] = fmaf(m, bflo(u.z), acc[4]); acc[5] = fmaf(m, bfhi(u.z), acc[5]);
        acc[6] = fmaf(m, bflo(u.w), acc[6]); acc[7] = fmaf(m, bfhi(u.w), acc[7]);
    }
    // butterfly over edge-slot dimension (lane bits 2..5)
    #pragma unroll
    for (int mask = 4; mask <= 32; mask <<= 1)
        #pragma unroll
        for (int j = 0; j < 8; j++)
            acc[j] += __shfl_xor(acc[j], mask, 64);
    if (e == 0) {
        float4* yo = (float4*)(y + (size_t)w * 32 + q * 8);
        yo[0] = make_float4(acc[0], acc[1], acc[2], acc[3]);
        yo[1] = make_float4(acc[4], acc[5], acc[6], acc[7]);
    }
}

// ---------------- GEMM K=19 (fp32 in [NN][32], fp32 compute, bf16 out, atomic stats) ----------------
template<int K>
__global__ __launch_bounds__(256) void k_gemm_small(const float* __restrict__ in,
        const float* __restrict__ W, const float* __restrict__ bias,
        unsigned short* __restrict__ out, float* __restrict__ gstat) {
    constexpr int SK = ((K + 3) / 4) * 4 + 4;
    __shared__ __align__(16) float yt[32 * SK];
    __shared__ float red[256];
    int tid = threadIdx.x;
    int row0 = blockIdx.x * 32;
    for (int t = tid; t < 32 * SK; t += 256) {
        int r = t / SK, k = t - r * SK;
        float v = 0.f;
        if (k < K) v = in[(size_t)(row0 + r) * 32 + k];
        yt[t] = v;
    }
    __syncthreads();
    int col = tid & 127;
    int rg = tid >> 7;
    float acc[16];
    #pragma unroll
    for (int r = 0; r < 16; r++) acc[r] = 0.f;
    const float* ybase = &yt[rg * 16 * SK];
    int kk = 0;
    for (; kk + 4 <= K; kk += 4) {
        float w0 = W[(kk + 0) * HH + col];
        float w1 = W[(kk + 1) * HH + col];
        float w2 = W[(kk + 2) * HH + col];
        float w3 = W[(kk + 3) * HH + col];
        #pragma unroll
        for (int r = 0; r < 16; r++) {
            const float4 v = *(const float4*)&ybase[r * SK + kk];
            acc[r] = fmaf(v.x, w0, acc[r]);
            acc[r] = fmaf(v.y, w1, acc[r]);
            acc[r] = fmaf(v.z, w2, acc[r]);
            acc[r] = fmaf(v.w, w3, acc[r]);
        }
    }
    if constexpr (K % 4 != 0) {
        float w[4];
        #pragma unroll
        for (int j = 0; j < 4; j++) w[j] = (kk + j < K) ? W[(kk + j) * HH + col] : 0.f;
        #pragma unroll
        for (int r = 0; r < 16; r++) {
            const float4 v = *(const float4*)&ybase[r * SK + kk];
            acc[r] = fmaf(v.x, w[0], acc[r]);
            acc[r] = fmaf(v.y, w[1], acc[r]);
            acc[r] = fmaf(v.z, w[2], acc[r]);
            acc[r] = fmaf(v.w, w[3], acc[r]);
        }
    }
    float bcol = bias[col];
    float s = 0.f, s2 = 0.f;
    #pragma unroll
    for (int r = 0; r < 16; r++) {
        float hv = acc[r] + bcol;
        out[(size_t)(row0 + rg * 16 + r) * HH + col] = (unsigned short)f2bfu(hv);
        s += hv; s2 = fmaf(hv, hv, s2);
    }
    int sl = (blockIdx.x & (STSLOT - 1)) << 8;
    red[tid] = s; __syncthreads();
    if (tid < 128) atomicAdd(&gstat[sl + tid], s + red[tid + 128]);
    __syncthreads();
    red[tid] = s2; __syncthreads();
    if (tid < 128) atomicAdd(&gstat[sl + 128 + tid], s2 + red[tid + 128]);
}

// ---------------- bf16 aggregation v2: 4 nodes per wave, 16-lane group owns a node ----------------
__global__ __launch_bounds__(256) void k_agg128_bf(const uint4* __restrict__ x4, const int* __restrict__ rp,
                                                   const int* __restrict__ srcs, uint4* __restrict__ y4) {
    int wave = (blockIdx.x * 256 + threadIdx.x) >> 6;
    int lane = threadIdx.x & 63;
    int g = lane >> 4, il = lane & 15;
    int w = wave * 4 + g;
    if (w >= NN) return;
    int beg = rp[w], end = rp[w + 1];
    // self row: group loads its node's row (16 lanes x 16B)
    uint4 u = x4[(size_t)w * 16 + il];
    float a0 = bflo(u.x), a1 = bfhi(u.x), a2 = bflo(u.y), a3 = bfhi(u.y);
    float a4 = bflo(u.z), a5 = bfhi(u.z), a6 = bflo(u.w), a7 = bfhi(u.w);
    float b0 = 0.f, b1 = 0.f, b2 = 0.f, b3 = 0.f, b4 = 0.f, b5 = 0.f, b6 = 0.f, b7 = 0.f;
    int p = beg;
    for (; p + 8 <= end; p += 8) {
        int s0 = srcs[p + 0], s1 = srcs[p + 1], s2 = srcs[p + 2], s3 = srcs[p + 3];
        int s4 = srcs[p + 4], s5 = srcs[p + 5], s6 = srcs[p + 6], s7 = srcs[p + 7];
        uint4 u0 = x4[(size_t)s0 * 16 + il];
        uint4 u1 = x4[(size_t)s1 * 16 + il];
        uint4 u2 = x4[(size_t)s2 * 16 + il];
        uint4 u3 = x4[(size_t)s3 * 16 + il];
        uint4 u4 = x4[(size_t)s4 * 16 + il];
        uint4 u5 = x4[(size_t)s5 * 16 + il];
        uint4 u6 = x4[(size_t)s6 * 16 + il];
        uint4 u7 = x4[(size_t)s7 * 16 + il];
        a0 += (bflo(u0.x) + bflo(u1.x)) + (bflo(u2.x) + bflo(u3.x));
        a1 += (bfhi(u0.x) + bfhi(u1.x)) + (bfhi(u2.x) + bfhi(u3.x));
        a2 += (bflo(u0.y) + bflo(u1.y)) + (bflo(u2.y) + bflo(u3.y));
        a3 += (bfhi(u0.y) + bfhi(u1.y)) + (bfhi(u2.y) + bfhi(u3.y));
        a4 += (bflo(u0.z) + bflo(u1.z)) + (bflo(u2.z) + bflo(u3.z));
        a5 += (bfhi(u0.z) + bfhi(u1.z)) + (bfhi(u2.z) + bfhi(u3.z));
        a6 += (bflo(u0.w) + bflo(u1.w)) + (bflo(u2.w) + bflo(u3.w));
        a7 += (bfhi(u0.w) + bfhi(u1.w)) + (bfhi(u2.w) + bfhi(u3.w));
        b0 += (bflo(u4.x) + bflo(u5.x)) + (bflo(u6.x) + bflo(u7.x));
        b1 += (bfhi(u4.x) + bfhi(u5.x)) + (bfhi(u6.x) + bfhi(u7.x));
        b2 += (bflo(u4.y) + bflo(u5.y)) + (bflo(u6.y) + bflo(u7.y));
        b3 += (bfhi(u4.y) + bfhi(u5.y)) + (bfhi(u6.y) + bfhi(u7.y));
        b4 += (bflo(u4.z) + bflo(u5.z)) + (bflo(u6.z) + bflo(u7.z));
        b5 += (bfhi(u4.z) + bfhi(u5.z)) + (bfhi(u6.z) + bfhi(u7.z));
        b6 += (bflo(u4.w) + bflo(u5.w)) + (bflo(u6.w) + bflo(u7.w));
        b7 += (bfhi(u4.w) + bfhi(u5.w)) + (bfhi(u6.w) + bfhi(u7.w));
    }
    for (; p + 4 <= end; p += 4) {
        int s0 = srcs[p + 0], s1 = srcs[p + 1], s2 = srcs[p + 2], s3 = srcs[p + 3];
        uint4 u0 = x4[(size_t)s0 * 16 + il];
        uint4 u1 = x4[(size_t)s1 * 16 + il];
        uint4 u2 = x4[(size_t)s2 * 16 + il];
        uint4 u3 = x4[(size_t)s3 * 16 + il];
        a0 += (bflo(u0.x) + bflo(u1.x)) + (bflo(u2.x) + bflo(u3.x));
        a1 += (bfhi(u0.x) + bfhi(u1.x)) + (bfhi(u2.x) + bfhi(u3.x));
        a2 += (bflo(u0.y) + bflo(u1.y)) + (bflo(u2.y) + bflo(u3.y));
        a3 += (bfhi(u0.y) + bfhi(u1.y)) + (bfhi(u2.y) + bfhi(u3.y));
        a4 += (bflo(u0.z) + bflo(u1.z)) + (bflo(u2.z) + bflo(u3.z));
        a5 += (bfhi(u0.z) + bfhi(u1.z)) + (bfhi(u2.z) + bfhi(u3.z));
        a6 += (bflo(u0.w) + bflo(u1.w)) + (bflo(u2.w) + bflo(u3.w));
        a7 += (bfhi(u0.w) + bfhi(u1.w)) + (bfhi(u2.w) + bfhi(u3.w));
    }
    for (; p < end; ++p) {
        uint4 uu = x4[(size_t)srcs[p] * 16 + il];
        a0 += bflo(uu.x); a1 += bfhi(uu.x);
        a2 += bflo(uu.y); a3 += bfhi(uu.y);
        a4 += bflo(uu.z); a5 += bfhi(uu.z);
        a6 += bflo(uu.w); a7 += bfhi(uu.w);
    }
    a0 += b0; a1 += b1; a2 += b2; a3 += b3;
    a4 += b4; a5 += b5; a6 += b6; a7 += b7;
    uint4 o;
    o.x = f2bfu(a0) | (f2bfu(a1) << 16);
    o.y = f2bfu(a2) | (f2bfu(a3) << 16);
    o.z = f2bfu(a4) | (f2bfu(a5) << 16);
    o.w = f2bfu(a6) | (f2bfu(a7) << 16);
    y4[(size_t)w * 16 + il] = o;
}

// ---------------- GEMM1: K=128 MFMA, LDS-staged A, bias out, atomic stats ----------------
__global__ __launch_bounds__(256) void k_gemm_s1(const unsigned short* __restrict__ in,
        const short* __restrict__ WT, const float* __restrict__ bias,
        unsigned short* __restrict__ out, float* __restrict__ gstat) {
    __shared__ __align__(16) short Al[64 * 136];
    __shared__ float lsum[HH], lsq[HH];
    int tid = threadIdx.x;
    if (tid < HH) { lsum[tid] = 0.f; lsq[tid] = 0.f; }
    int row0 = blockIdx.x * 64;
    {
        int r = tid >> 2;
        int k0 = (tid & 3) * 32;
        int grow = row0 + r;
        uint4* d4 = (uint4*)&Al[r * 136 + k0];
        if (grow < NN) {
            const uint4* s4 = (const uint4*)(in + (size_t)grow * HH + k0);
            d4[0] = s4[0]; d4[1] = s4[1]; d4[2] = s4[2]; d4[3] = s4[3];
        } else {
            uint4 z = {0, 0, 0, 0};
            d4[0] = z; d4[1] = z; d4[2] = z; d4[3] = z;
        }
    }
    __syncthreads();
    int wave = tid >> 6;
    int lane = tid & 63;
    int ln = lane & 15, quad = lane >> 4;
    int wcol0 = wave * 32;
    f32x4 acc[4][2];
    #pragma unroll
    for (int rt = 0; rt < 4; rt++)
        #pragma unroll
        for (int ct = 0; ct < 2; ct++) acc[rt][ct] = (f32x4){0.f, 0.f, 0.f, 0.f};
    #pragma unroll
    for (int ks = 0; ks < 4; ks++) {
        bf16x8 a[4], b[2];
        #pragma unroll
        for (int ct = 0; ct < 2; ct++)
            b[ct] = *(const bf16x8*)(WT + (size_t)(wcol0 + ct * 16 + ln) * HH + ks * 32 + quad * 8);
        #pragma unroll
        for (int rt = 0; rt < 4; rt++)
            a[rt] = *(const bf16x8*)(&Al[(rt * 16 + ln) * 136 + ks * 32 + quad * 8]);
        #pragma unroll
        for (int rt = 0; rt < 4; rt++)
            #pragma unroll
            for (int ct = 0; ct < 2; ct++)
                acc[rt][ct] = __builtin_amdgcn_mfma_f32_16x16x32_bf16(a[rt], b[ct], acc[rt][ct], 0, 0, 0);
    }
    float b0 = bias[wcol0 + ln];
    float b1 = bias[wcol0 + 16 + ln];
    float s[2] = {0.f, 0.f}, s2[2] = {0.f, 0.f};
    #pragma unroll
    for (int rt = 0; rt < 4; rt++) {
        #pragma unroll
        for (int r = 0; r < 4; r++) {
            int grow = row0 + rt * 16 + quad * 4 + r;
            if (grow < NN) {
                float hv0 = acc[rt][0][r] + b0;
                float hv1 = acc[rt][1][r] + b1;
                out[(size_t)grow * HH + wcol0 + ln] = (unsigned short)f2bfu(hv0);
                out[(size_t)grow * HH + wcol0 + 16 + ln] = (unsigned short)f2bfu(hv1);
                s[0] += hv0; s2[0] = fmaf(hv0, hv0, s2[0]);
                s[1] += hv1; s2[1] = fmaf(hv1, hv1, s2[1]);
            }
        }
    }
    atomicAdd(&lsum[wcol0 + ln], s[0]);
    atomicAdd(&lsum[wcol0 + 16 + ln], s[1]);
    atomicAdd(&lsq[wcol0 + ln], s2[0]);
    atomicAdd(&lsq[wcol0 + 16 + ln], s2[1]);
    __syncthreads();
    if (tid < HH) {
        int sl = (blockIdx.x & (STSLOT - 1)) << 8;
        atomicAdd(&gstat[sl + tid], lsum[tid]);
        atomicAdd(&gstat[sl + 128 + tid], lsq[tid]);
    }
}

// ---------------- GEMM2: BN affine + ReLU on load, ELU out; optional fused mean/max pooling ----------------
template<bool POOL>
__global__ __launch_bounds__(256) void k_gemm_bn(const unsigned short* __restrict__ in,
        const short* __restrict__ WT, const float* __restrict__ bias,
        const float* __restrict__ gstat, const float* __restrict__ gm, const float* __restrict__ bt,
        unsigned short* __restrict__ out, const int* __restrict__ batch,
        float* __restrict__ psumG, unsigned* __restrict__ pmaxG) {
    __shared__ __align__(16) short Al[64 * 136];
    __shared__ __align__(16) float bnsc[HH], bnsh[HH];
    int tid = threadIdx.x;
    if (tid < HH) {
        float s = 0.f, s2 = 0.f;
        #pragma unroll
        for (int k = 0; k < STSLOT; ++k) {
            s += gstat[(k << 8) + tid];
            s2 += gstat[(k << 8) + 128 + tid];
        }
        float mu = s * (1.f / NN);
        float var = fmaxf(s2 * (1.f / NN) - mu * mu, 0.f);
        float a = gm[tid] * rsqrtf(var + BN_EPS);
        bnsc[tid] = a;
        bnsh[tid] = fmaf(-mu, a, bt[tid]);
    }
    __syncthreads();
    int row0 = blockIdx.x * 64;
    {
        int r = tid >> 2;
        int k0 = (tid & 3) * 32;
        int grow = row0 + r;
        short* dst = &Al[r * 136 + k0];
        if (grow < NN) {
            const uint4* s4 = (const uint4*)(in + (size_t)grow * HH + k0);
            unsigned* d = (unsigned*)dst;
            #pragma unroll
            for (int q = 0; q < 4; q++) {
                uint4 u = s4[q];
                float4 sc0 = *(const float4*)(bnsc + k0 + q * 8);
                float4 sh0 = *(const float4*)(bnsh + k0 + q * 8);
                float4 sc1 = *(const float4*)(bnsc + k0 + q * 8 + 4);
                float4 sh1 = *(const float4*)(bnsh + k0 + q * 8 + 4);
                float a0 = bflo(u.x), a1 = bfhi(u.x);
                float a2 = bflo(u.y), a3 = bfhi(u.y);
                float a4 = bflo(u.z), a5 = bfhi(u.z);
                float a6 = bflo(u.w), a7 = bfhi(u.w);
                a0 = fmaxf(fmaf(a0, sc0.x, sh0.x), 0.f);
                a1 = fmaxf(fmaf(a1, sc0.y, sh0.y), 0.f);
                a2 = fmaxf(fmaf(a2, sc0.z, sh0.z), 0.f);
                a3 = fmaxf(fmaf(a3, sc0.w, sh0.w), 0.f);
                a4 = fmaxf(fmaf(a4, sc1.x, sh1.x), 0.f);
                a5 = fmaxf(fmaf(a5, sc1.y, sh1.y), 0.f);
                a6 = fmaxf(fmaf(a6, sc1.z, sh1.z), 0.f);
                a7 = fmaxf(fmaf(a7, sc1.w, sh1.w), 0.f);
                d[q * 4 + 0] = f2bfu(a0) | (f2bfu(a1) << 16);
                d[q * 4 + 1] = f2bfu(a2) | (f2bfu(a3) << 16);
                d[q * 4 + 2] = f2bfu(a4) | (f2bfu(a5) << 16);
                d[q * 4 + 3] = f2bfu(a6) | (f2bfu(a7) << 16);
            }
        } else {
            uint4 z = {0, 0, 0, 0};
            uint4* d4 = (uint4*)dst;
            d4[0] = z; d4[1] = z; d4[2] = z; d4[3] = z;
        }
    }
    __syncthreads();
    int wave = tid >> 6;
    int lane = tid & 63;
    int ln = lane & 15, quad = lane >> 4;
    int wcol0 = wave * 32;
    f32x4 acc[4][2];
    #pragma unroll
    for (int rt = 0; rt < 4; rt++)
        #pragma unroll
        for (int ct = 0; ct < 2; ct++) acc[rt][ct] = (f32x4){0.f, 0.f, 0.f, 0.f};
    #pragma unroll
    for (int ks = 0; ks < 4; ks++) {
        bf16x8 a[4], b[2];
        #pragma unroll
        for (int ct = 0; ct < 2; ct++)
            b[ct] = *(const bf16x8*)(WT + (size_t)(wcol0 + ct * 16 + ln) * HH + ks * 32 + quad * 8);
        #pragma unroll
        for (int rt = 0; rt < 4; rt++)
            a[rt] = *(const bf16x8*)(&Al[(rt * 16 + ln) * 136 + ks * 32 + quad * 8]);
        #pragma unroll
        for (int rt = 0; rt < 4; rt++)
            #pragma unroll
            for (int ct = 0; ct < 2; ct++)
                acc[rt][ct] = __builtin_amdgcn_mfma_f32_16x16x32_bf16(a[rt], b[ct], acc[rt][ct], 0, 0, 0);
    }
    float b0 = bias[wcol0 + ln];
    float b1 = bias[wcol0 + 16 + ln];
    // pooling state (POOL only): fast path when whole block is one graph
    bool uni = false;
    int g0_ = 0;
    float ps0 = 0.f, ps1 = 0.f, pm0 = -INFINITY, pm1 = -INFINITY;
    if (POOL) {
        int rlast = min(row0 + 63, NN - 1);
        g0_ = batch[row0 < NN ? row0 : NN - 1];
        uni = (batch[rlast] == g0_);
    }
    #pragma unroll
    for (int rt = 0; rt < 4; rt++) {
        #pragma unroll
        for (int r = 0; r < 4; r++) {
            int grow = row0 + rt * 16 + quad * 4 + r;
            if (grow < NN) {
                float hv0 = elu01f(acc[rt][0][r] + b0);
                float hv1 = elu01f(acc[rt][1][r] + b1);
                out[(size_t)grow * HH + wcol0 + ln] = (unsigned short)f2bfu(hv0);
                out[(size_t)grow * HH + wcol0 + 16 + ln] = (unsigned short)f2bfu(hv1);
                if (POOL) {
                    // match pooling input precision: pooled values are the bf16-rounded outputs
                    float q0 = bfu2f((unsigned short)f2bfu(hv0));
                    float q1 = bfu2f((unsigned short)f2bfu(hv1));
                    if (uni) {
                        ps0 += q0; ps1 += q1;
                        pm0 = fmaxf(pm0, q0); pm1 = fmaxf(pm1, q1);
                    } else {
                        int gph = batch[grow];
                        atomicAdd(&psumG[gph * HH + wcol0 + ln], q0);
                        atomicAdd(&psumG[gph * HH + wcol0 + 16 + ln], q1);
                        atomicMax(&pmaxG[gph * HH + wcol0 + ln], fenc(q0));
                        atomicMax(&pmaxG[gph * HH + wcol0 + 16 + ln], fenc(q1));
                    }
                }
            }
        }
    }
    if (POOL && uni) {
        atomicAdd(&psumG[g0_ * HH + wcol0 + ln], ps0);
        atomicAdd(&psumG[g0_ * HH + wcol0 + 16 + ln], ps1);
        atomicMax(&pmaxG[g0_ * HH + wcol0 + ln], fenc(pm0));
        atomicMax(&pmaxG[g0_ * HH + wcol0 + 16 + ln], fenc(pm1));
    }
}

// pool finalize (reads fused per-graph sums/maxes) + classifier layer 1 (one block per graph)
__global__ __launch_bounds__(128) void k_pool_cls1(const float* __restrict__ psumG, const unsigned* __restrict__ pmaxG,
                                                   const int* __restrict__ gptr, const float* __restrict__ g0,
                                                   const float* __restrict__ cw1, const float* __restrict__ cb1,
                                                   float* __restrict__ z1) {
    __shared__ float zr[264];
    int g = blockIdx.x, c = threadIdx.x;
    int cntn = gptr[g + 1] - gptr[g];
    zr[c] = psumG[g * HH + c] / (float)max(cntn, 1);
    zr[128 + c] = fdec(pmaxG[g * HH + c]);
    if (c < GG) zr[256 + c] = g0[g * GG + c];
    __syncthreads();
    float acc = cb1[c];
    for (int k = 0; k < 264; ++k) acc = fmaf(zr[k], cw1[k * HH + c], acc);
    z1[g * HH + c] = elu01f(acc);
}

__global__ __launch_bounds__(128) void k_cls2(const float* __restrict__ z1, const float* __restrict__ cgm,
                                              const float* __restrict__ cbt, const float* __restrict__ cw2,
                                              const float* __restrict__ cb2, float* __restrict__ outp) {
    __shared__ float zn[HH * 65];
    int c = threadIdx.x;
    float s = 0.f, s2 = 0.f;
    for (int g = 0; g < BB; ++g) {
        float v = z1[g * HH + c];
        s += v; s2 = fmaf(v, v, s2);
    }
    float mu = s * (1.f / BB);
    float var = fmaxf(s2 * (1.f / BB) - mu * mu, 0.f);
    float a = cgm[c] * rsqrtf(var + BN_EPS);
    float sh = fmaf(-mu, a, cbt[c]);
    for (int g = 0; g < BB; ++g) zn[c * 65 + g] = fmaf(z1[g * HH + c], a, sh);
    __syncthreads();
    if (c < BB) {
        float l0 = cb2[0], l1 = cb2[1];
        for (int k = 0; k < HH; ++k) {
            float v = zn[k * 65 + c];
            l0 = fmaf(v, cw2[k * 2 + 0], l0);
            l1 = fmaf(v, cw2[k * 2 + 1], l1);
        }
        float m = fmaxf(l0, l1);
        float e0 = __expf(l0 - m), e1 = __expf(l1 - m);
        float inv = 1.f / (e0 + e1);
        outp[c * 2 + 0] = e0 * inv;
        outp[c * 2 + 1] = e1 * inv;
    }
}

extern "C" void kernel_launch(void* const* d_in, const int* in_sizes, int n_in,
                              void* d_out, int out_size, void* d_ws, size_t ws_size,
                              hipStream_t stream) {
    (void)in_sizes; (void)n_in; (void)out_size; (void)ws_size;
    const float* h0     = (const float*)d_in[0];
    const float* coord0 = (const float*)d_in[1];
    const float* g0     = (const float*)d_in[2];
    const int*   eidx   = (const int*)d_in[3];
    const int*   batch  = (const int*)d_in[4];
    const float* w1_0   = (const float*)d_in[5];
    const float* b1_0   = (const float*)d_in[6];
    const float* gm_0   = (const float*)d_in[7];
    const float* bt_0   = (const float*)d_in[8];
    const float* w2_0   = (const float*)d_in[9];
    const float* b2_0   = (const float*)d_in[10];
    const float* w1_r   = (const float*)d_in[11];
    const float* b1_r   = (const float*)d_in[12];
    const float* gm_r   = (const float*)d_in[13];
    const float* bt_r   = (const float*)d_in[14];
    const float* w2_r   = (const float*)d_in[15];
    const float* b2_r   = (const float*)d_in[16];
    const float* cw1    = (const float*)d_in[17];
    const float* cb1    = (const float*)d_in[18];
    const float* cgm    = (const float*)d_in[19];
    const float* cbt    = (const float*)d_in[20];
    const float* cw2    = (const float*)d_in[21];
    const float* cb2    = (const float*)d_in[22];
    float* outp = (float*)d_out;

    const int* esrc = eidx;
    const int* edst = eidx + EE;

    char* p = (char*)d_ws;
    auto alloc = [&](size_t bytes) { void* r = (void*)p; p += (bytes + 255) & ~(size_t)255; return r; };
    int*            bincnt   = (int*)alloc((size_t)NBINS * 4);                 // }
    float*          gstat    = (float*)alloc((size_t)3 * STSLOT * 256 * 4);    // } one memset region
    float*          psumG    = (float*)alloc((size_t)BB * HH * 4);             // }
    unsigned*       pmaxG    = (unsigned*)alloc((size_t)BB * HH * 4);          // } (0 == -inf encoded)
    unsigned short* x0bf     = (unsigned short*)alloc((size_t)NN * 32 * 2);    // [NN][32] bf16
    float*          y19f     = (float*)alloc((size_t)NN * 32 * 4);             // [NN][32] f32
    unsigned short* hbf      = (unsigned short*)alloc((size_t)NN * HH * 2);
    unsigned*       xbf      = (unsigned*)alloc((size_t)NN * 64 * 4);
    unsigned*       ybf      = (unsigned*)alloc((size_t)NN * 64 * 4);
    int*            rp       = (int*)alloc((size_t)(NN + 1) * 4);
    int*            srcs     = (int*)alloc((size_t)EE * 4);
    int*            gptr     = (int*)alloc((BB + 1) * 4);
    short*          wt       = (short*)alloc((size_t)5 * HH * HH * 2);
    float*          z1b      = (float*)alloc((size_t)BB * HH * 4);
    uint2*          binbuf   = (uint2*)alloc((size_t)NBINS * BCAP * 8);        // 25.7 MB, own region

    const int NB_A = (EE + ACH - 1) / ACH;          // 782
    const int NB_AGG = (NN * 64 + 255) / 256;       // 25000 (wave per node, layer 0)
    const int NB_AGG4 = (NN + 15) / 16;             // 6250  (4 nodes per wave, layers 1..2)
    const int NB_G32 = NN / 32;                     // 3125
    const int NB_G64 = (NN + 63) / 64;              // 1563

    size_t zlen = (size_t)((char*)x0bf - (char*)bincnt);   // bincnt + gstat + psumG + pmaxG
    hipMemsetAsync(bincnt, 0, zlen, stream);

    // CSR build (LDS counting sort, 512 threads) + weight prep + feature build + gptr
    k_binA<<<NB_A, 512, 0, stream>>>(esrc, edst, bincnt, binbuf);
    k_binB<<<NBINS, 512, 0, stream>>>(binbuf, bincnt, rp, srcs);
    k_prep<<<NB_WP + NB_X0, 256, 0, stream>>>(w2_0, w1_r, w2_r, wt, h0, coord0, x0bf, batch, gptr);

    // layer 0: split agg (wave/node) -> f32 y19 -> K=19 GEMM (stats) -> GEMM2 (BN from raw stats)
    k_agg_small<<<NB_AGG, 256, 0, stream>>>((const uint4*)x0bf, rp, srcs, y19f);
    k_gemm_small<K0><<<NB_G32, 256, 0, stream>>>(y19f, w1_0, b1_0, hbf, gstat);
    k_gemm_bn<false><<<NB_G64, 256, 0, stream>>>(hbf, wt, b2_0, gstat, gm_0, bt_0,
                                                 (unsigned short*)xbf, batch, psumG, pmaxG);

    // layers 1..2: grouped agg (4 nodes/wave) + MFMA GEMM with atomic stats; last BN-GEMM fuses pooling
    for (int i = 0; i < 2; ++i) {
        float* gs = gstat + (size_t)(1 + i) * STSLOT * 256;
        k_agg128_bf<<<NB_AGG4, 256, 0, stream>>>((const uint4*)xbf, rp, srcs, (uint4*)ybf);
        k_gemm_s1<<<NB_G64, 256, 0, stream>>>((const unsigned short*)ybf,
                wt + (size_t)(1 + i) * HH * HH, b1_r + i * HH, hbf, gs);
        if (i == 0)
            k_gemm_bn<false><<<NB_G64, 256, 0, stream>>>(hbf, wt + (size_t)(3 + i) * HH * HH,
                    b2_r + i * HH, gs, gm_r + i * HH, bt_r + i * HH,
                    (unsigned short*)xbf, batch, psumG, pmaxG);
        else
            k_gemm_bn<true><<<NB_G64, 256, 0, stream>>>(hbf, wt + (size_t)(3 + i) * HH * HH,
                    b2_r + i * HH, gs, gm_r + i * HH, bt_r + i * HH,
                    (unsigned short*)xbf, batch, psumG, pmaxG);
    }

    // classifier (pooling already accumulated into psumG/pmaxG)
    k_pool_cls1<<<BB, 128, 0, stream>>>(psumG, pmaxG, gptr, g0, cw1, cb1, z1b);
    k_cls2<<<1, 128, 0, stream>>>(z1b, cgm, cbt, cw2, cb2, outp);
}

// Round 12
// 484.036 us; speedup vs baseline: 1.0529x; 1.0529x over previous
//
#include <hip/hip_runtime.h>
#include <math.h>

#define NN 100000
#define EE 1600000
#define BB 64
#define FF 16
#define HH 128
#define GG 8
#define K0 19
#define BN_EPS 1e-5f
#define PCH 16
#define BSHIFT 8
#define BNODES 256
#define NBINS 391          // ceil(NN/256)
#define BCAP 8192
#define ACH 2048           // edges per phase-A block
#define NB_WP 320          // (5*HH*HH+255)/256
#define NB_X0 12500        // NN*32/256
#define STSLOT 8           // atomic-stat shadow copies

typedef short bf16x8 __attribute__((ext_vector_type(8)));
typedef float f32x4 __attribute__((ext_vector_type(4)));

__device__ __forceinline__ float elu01f(float v) {
    return v > 0.f ? v : 0.1f * (__expf(v) - 1.f);
}

__device__ __forceinline__ unsigned f2bfu(float f) {
    unsigned u = __float_as_uint(f);
    unsigned r = u + 0x7FFFu + ((u >> 16) & 1u);
    return r >> 16;
}
__device__ __forceinline__ short f2bf(float f) { return (short)f2bfu(f); }
__device__ __forceinline__ float bfu2f(unsigned short b) {
    return __uint_as_float(((unsigned)b) << 16);
}
__device__ __forceinline__ float bflo(unsigned u) { return __uint_as_float(u << 16); }
__device__ __forceinline__ float bfhi(unsigned u) { return __uint_as_float(u & 0xffff0000u); }

// ---------------- CSR build: 2-phase LDS counting sort (512 threads) ----------------
__global__ __launch_bounds__(512) void k_binA(const int* __restrict__ esrc, const int* __restrict__ edst,
                                              int* __restrict__ bincnt, uint2* __restrict__ binbuf) {
    __shared__ int hist[NBINS];
    __shared__ int gbase[NBINS];
    __shared__ int cur[NBINS];
    __shared__ int sc[512];
    __shared__ uint2 ebuf[ACH];
    __shared__ uint2 sorted[ACH];
    int tid = threadIdx.x;
    int e0 = blockIdx.x * ACH;
    int n = min(ACH, EE - e0);
    if (tid < NBINS) hist[tid] = 0;
    __syncthreads();
    for (int i = tid; i < n; i += 512) {
        int s = esrc[e0 + i];
        int d = edst[e0 + i];
        ebuf[i] = make_uint2((unsigned)s, (unsigned)d);
        atomicAdd(&hist[d >> BSHIFT], 1);
    }
    __syncthreads();
    sc[tid] = (tid < NBINS) ? hist[tid] : 0;
    __syncthreads();
    for (int off = 1; off < 512; off <<= 1) {
        int v = (tid >= off) ? sc[tid - off] : 0;
        __syncthreads();
        sc[tid] += v;
        __syncthreads();
    }
    if (tid < NBINS) {
        int c = hist[tid];
        gbase[tid] = (c > 0) ? atomicAdd(&bincnt[tid], c) : 0;
        cur[tid] = (tid > 0) ? sc[tid - 1] : 0;
    }
    __syncthreads();
    for (int i = tid; i < n; i += 512) {
        uint2 e = ebuf[i];
        int b = (int)(e.y >> BSHIFT);
        int pos = atomicAdd(&cur[b], 1);
        sorted[pos] = e;
    }
    __syncthreads();
    for (int i = tid; i < n; i += 512) {
        uint2 e = sorted[i];
        int b = (int)(e.y >> BSHIFT);
        int ls = (b > 0) ? sc[b - 1] : 0;
        int gpos = gbase[b] + (i - ls);
        binbuf[(size_t)b * BCAP + gpos] = e;
    }
}

// phase B: per-bin counting sort; block computes its own global base from bincnt (512 threads)
__global__ __launch_bounds__(512) void k_binB(const uint2* __restrict__ binbuf, const int* __restrict__ bincnt,
                                              int* __restrict__ rp, int* __restrict__ srcs) {
    __shared__ int hist[BNODES];
    __shared__ int scx[BNODES];
    __shared__ int scur[BNODES];
    __shared__ int rsum[512];
    __shared__ int sbuf[BCAP];
    int b = blockIdx.x;
    int n = bincnt[b];
    int tid = threadIdx.x;
    // base = sum bincnt[0..b-1]
    rsum[tid] = (tid < b) ? bincnt[tid] : 0;
    if (tid < BNODES) hist[tid] = 0;
    __syncthreads();
    for (int off = 256; off > 0; off >>= 1) {
        if (tid < off) rsum[tid] += rsum[tid + off];
        __syncthreads();
    }
    int base = rsum[0];
    const uint2* eb = binbuf + (size_t)b * BCAP;
    for (int i = tid; i < n; i += 512)
        atomicAdd(&hist[eb[i].y & (BNODES - 1)], 1);
    __syncthreads();
    if (tid < BNODES) scx[tid] = hist[tid];
    __syncthreads();
    for (int off = 1; off < BNODES; off <<= 1) {
        int vv = (tid >= off && tid < BNODES) ? scx[tid - off] : 0;
        __syncthreads();
        if (tid < BNODES) scx[tid] += vv;
        __syncthreads();
    }
    if (tid < BNODES) {
        int excl = (tid > 0) ? scx[tid - 1] : 0;
        int node = (b << BSHIFT) + tid;
        if (node < NN) rp[node] = base + excl;
        scur[tid] = excl;
    }
    if (b == NBINS - 1 && tid == 0) rp[NN] = EE;
    __syncthreads();
    for (int i = tid; i < n; i += 512) {
        uint2 e = eb[i];
        int pos = atomicAdd(&scur[e.y & (BNODES - 1)], 1);
        sbuf[pos] = (int)e.x;
    }
    __syncthreads();
    for (int i = tid; i < n; i += 512) srcs[base + i] = sbuf[i];
}

// ---------------- merged prep: weight transpose + x0 feature build + gptr search ----------------
__global__ __launch_bounds__(256) void k_prep(const float* __restrict__ w2_0, const float* __restrict__ w1_r,
                                              const float* __restrict__ w2_r, short* __restrict__ wt,
                                              const float* __restrict__ h0, const float* __restrict__ coord,
                                              unsigned short* __restrict__ x0,
                                              const int* __restrict__ batch, int* __restrict__ gptr) {
    int b = blockIdx.x;
    int tid = threadIdx.x;
    if (b == 0 && tid <= BB) {
        int t = tid;
        int lo = 0, hi = NN;
        while (lo < hi) { int mid = (lo + hi) >> 1; if (batch[mid] < t) lo = mid + 1; else hi = mid; }
        gptr[t] = lo;
    }
    if (b < NB_WP) {
        int t = b * 256 + tid;
        if (t >= 5 * HH * HH) return;
        int m = t >> 14;
        int rem = t & 16383;
        int col = rem >> 7;
        int k = rem & 127;
        const float* src = (m == 0) ? w2_0 : (m <= 2 ? w1_r + (size_t)(m - 1) * HH * HH
                                                     : w2_r + (size_t)(m - 3) * HH * HH);
        wt[t] = f2bf(src[k * HH + col]);
    } else {
        int i = (b - NB_WP) * 256 + tid;
        if (i >= NN * 32) return;
        int node = i >> 5, k = i & 31;
        float v = 0.f;
        if (k < FF) v = h0[node * FF + k];
        else if (k < K0) v = coord[node * 3 + (k - FF)];
        x0[i] = (unsigned short)f2bfu(v);
    }
}

// ---------------- layer-0 aggregation: wave per node, 16 edges in flight, f32 out ----------------
__global__ __launch_bounds__(256) void k_agg_small(const uint4* __restrict__ x, const int* __restrict__ rp,
                                                   const int* __restrict__ srcs, float* __restrict__ y) {
    int w = (blockIdx.x * 256 + threadIdx.x) >> 6;
    int lane = threadIdx.x & 63;
    if (w >= NN) return;
    int e = lane >> 2, q = lane & 3;
    int beg = rp[w], end = rp[w + 1];
    float acc[8];
    {   // self row on e==0 lanes
        if (e == 0) {
            uint4 u = x[(size_t)w * 4 + q];
            acc[0] = bflo(u.x); acc[1] = bfhi(u.x);
            acc[2] = bflo(u.y); acc[3] = bfhi(u.y);
            acc[4] = bflo(u.z); acc[5] = bfhi(u.z);
            acc[6] = bflo(u.w); acc[7] = bfhi(u.w);
        } else {
            #pragma unroll
            for (int j = 0; j < 8; j++) acc[j] = 0.f;
        }
    }
    for (int p = beg; p < end; p += 16) {
        int rem = end - p;
        bool act = e < rem;
        int sn = act ? srcs[p + e] : 0;
        uint4 u = x[(size_t)sn * 4 + q];
        float m = act ? 1.f : 0.f;
        acc[0] = fmaf(m, bflo(u.x), acc[0]); acc[1] = fmaf(m, bfhi(u.x), acc[1]);
        acc[2] = fmaf(m, bflo(u.y), acc[2]); acc[3] = fmaf(m, bfhi(u.y), acc[3]);
        acc[4] = fmaf(m, bflo(u.z), acc[4]); acc[5] = fmaf(m, bfhi(u.z), acc[5]);
        acc[6] = fmaf(m, bflo(u.w), acc[6]); acc[7] = fmaf(m, bfhi(u.w), acc[7]);
    }
    // butterfly over edge-slot dimension (lane bits 2..5)
    #pragma unroll
    for (int mask = 4; mask <= 32; mask <<= 1)
        #pragma unroll
        for (int j = 0; j < 8; j++)
            acc[j] += __shfl_xor(acc[j], mask, 64);
    if (e == 0) {
        float4* yo = (float4*)(y + (size_t)w * 32 + q * 8);
        yo[0] = make_float4(acc[0], acc[1], acc[2], acc[3]);
        yo[1] = make_float4(acc[4], acc[5], acc[6], acc[7]);
    }
}

// ---------------- GEMM K=19 (fp32 in [NN][32], fp32 compute, bf16 out, atomic stats) ----------------
template<int K>
__global__ __launch_bounds__(256) void k_gemm_small(const float* __restrict__ in,
        const float* __restrict__ W, const float* __restrict__ bias,
        unsigned short* __restrict__ out, float* __restrict__ gstat) {
    constexpr int SK = ((K + 3) / 4) * 4 + 4;
    __shared__ __align__(16) float yt[32 * SK];
    __shared__ float red[256];
    int tid = threadIdx.x;
    int row0 = blockIdx.x * 32;
    for (int t = tid; t < 32 * SK; t += 256) {
        int r = t / SK, k = t - r * SK;
        float v = 0.f;
        if (k < K) v = in[(size_t)(row0 + r) * 32 + k];
        yt[t] = v;
    }
    __syncthreads();
    int col = tid & 127;
    int rg = tid >> 7;
    float acc[16];
    #pragma unroll
    for (int r = 0; r < 16; r++) acc[r] = 0.f;
    const float* ybase = &yt[rg * 16 * SK];
    int kk = 0;
    for (; kk + 4 <= K; kk += 4) {
        float w0 = W[(kk + 0) * HH + col];
        float w1 = W[(kk + 1) * HH + col];
        float w2 = W[(kk + 2) * HH + col];
        float w3 = W[(kk + 3) * HH + col];
        #pragma unroll
        for (int r = 0; r < 16; r++) {
            const float4 v = *(const float4*)&ybase[r * SK + kk];
            acc[r] = fmaf(v.x, w0, acc[r]);
            acc[r] = fmaf(v.y, w1, acc[r]);
            acc[r] = fmaf(v.z, w2, acc[r]);
            acc[r] = fmaf(v.w, w3, acc[r]);
        }
    }
    if constexpr (K % 4 != 0) {
        float w[4];
        #pragma unroll
        for (int j = 0; j < 4; j++) w[j] = (kk + j < K) ? W[(kk + j) * HH + col] : 0.f;
        #pragma unroll
        for (int r = 0; r < 16; r++) {
            const float4 v = *(const float4*)&ybase[r * SK + kk];
            acc[r] = fmaf(v.x, w[0], acc[r]);
            acc[r] = fmaf(v.y, w[1], acc[r]);
            acc[r] = fmaf(v.z, w[2], acc[r]);
            acc[r] = fmaf(v.w, w[3], acc[r]);
        }
    }
    float bcol = bias[col];
    float s = 0.f, s2 = 0.f;
    #pragma unroll
    for (int r = 0; r < 16; r++) {
        float hv = acc[r] + bcol;
        out[(size_t)(row0 + rg * 16 + r) * HH + col] = (unsigned short)f2bfu(hv);
        s += hv; s2 = fmaf(hv, hv, s2);
    }
    int sl = (blockIdx.x & (STSLOT - 1)) << 8;
    red[tid] = s; __syncthreads();
    if (tid < 128) atomicAdd(&gstat[sl + tid], s + red[tid + 128]);
    __syncthreads();
    red[tid] = s2; __syncthreads();
    if (tid < 128) atomicAdd(&gstat[sl + 128 + tid], s2 + red[tid + 128]);
}

// ---------------- bf16 aggregation v2: 4 nodes per wave, 16-lane group owns a node ----------------
__global__ __launch_bounds__(256) void k_agg128_bf(const uint4* __restrict__ x4, const int* __restrict__ rp,
                                                   const int* __restrict__ srcs, uint4* __restrict__ y4) {
    int wave = (blockIdx.x * 256 + threadIdx.x) >> 6;
    int lane = threadIdx.x & 63;
    int g = lane >> 4, il = lane & 15;
    int w = wave * 4 + g;
    if (w >= NN) return;
    int beg = rp[w], end = rp[w + 1];
    // self row: group loads its node's row (16 lanes x 16B)
    uint4 u = x4[(size_t)w * 16 + il];
    float a0 = bflo(u.x), a1 = bfhi(u.x), a2 = bflo(u.y), a3 = bfhi(u.y);
    float a4 = bflo(u.z), a5 = bfhi(u.z), a6 = bflo(u.w), a7 = bfhi(u.w);
    float b0 = 0.f, b1 = 0.f, b2 = 0.f, b3 = 0.f, b4 = 0.f, b5 = 0.f, b6 = 0.f, b7 = 0.f;
    int p = beg;
    for (; p + 8 <= end; p += 8) {
        int s0 = srcs[p + 0], s1 = srcs[p + 1], s2 = srcs[p + 2], s3 = srcs[p + 3];
        int s4 = srcs[p + 4], s5 = srcs[p + 5], s6 = srcs[p + 6], s7 = srcs[p + 7];
        uint4 u0 = x4[(size_t)s0 * 16 + il];
        uint4 u1 = x4[(size_t)s1 * 16 + il];
        uint4 u2 = x4[(size_t)s2 * 16 + il];
        uint4 u3 = x4[(size_t)s3 * 16 + il];
        uint4 u4 = x4[(size_t)s4 * 16 + il];
        uint4 u5 = x4[(size_t)s5 * 16 + il];
        uint4 u6 = x4[(size_t)s6 * 16 + il];
        uint4 u7 = x4[(size_t)s7 * 16 + il];
        a0 += (bflo(u0.x) + bflo(u1.x)) + (bflo(u2.x) + bflo(u3.x));
        a1 += (bfhi(u0.x) + bfhi(u1.x)) + (bfhi(u2.x) + bfhi(u3.x));
        a2 += (bflo(u0.y) + bflo(u1.y)) + (bflo(u2.y) + bflo(u3.y));
        a3 += (bfhi(u0.y) + bfhi(u1.y)) + (bfhi(u2.y) + bfhi(u3.y));
        a4 += (bflo(u0.z) + bflo(u1.z)) + (bflo(u2.z) + bflo(u3.z));
        a5 += (bfhi(u0.z) + bfhi(u1.z)) + (bfhi(u2.z) + bfhi(u3.z));
        a6 += (bflo(u0.w) + bflo(u1.w)) + (bflo(u2.w) + bflo(u3.w));
        a7 += (bfhi(u0.w) + bfhi(u1.w)) + (bfhi(u2.w) + bfhi(u3.w));
        b0 += (bflo(u4.x) + bflo(u5.x)) + (bflo(u6.x) + bflo(u7.x));
        b1 += (bfhi(u4.x) + bfhi(u5.x)) + (bfhi(u6.x) + bfhi(u7.x));
        b2 += (bflo(u4.y) + bflo(u5.y)) + (bflo(u6.y) + bflo(u7.y));
        b3 += (bfhi(u4.y) + bfhi(u5.y)) + (bfhi(u6.y) + bfhi(u7.y));
        b4 += (bflo(u4.z) + bflo(u5.z)) + (bflo(u6.z) + bflo(u7.z));
        b5 += (bfhi(u4.z) + bfhi(u5.z)) + (bfhi(u6.z) + bfhi(u7.z));
        b6 += (bflo(u4.w) + bflo(u5.w)) + (bflo(u6.w) + bflo(u7.w));
        b7 += (bfhi(u4.w) + bfhi(u5.w)) + (bfhi(u6.w) + bfhi(u7.w));
    }
    for (; p + 4 <= end; p += 4) {
        int s0 = srcs[p + 0], s1 = srcs[p + 1], s2 = srcs[p + 2], s3 = srcs[p + 3];
        uint4 u0 = x4[(size_t)s0 * 16 + il];
        uint4 u1 = x4[(size_t)s1 * 16 + il];
        uint4 u2 = x4[(size_t)s2 * 16 + il];
        uint4 u3 = x4[(size_t)s3 * 16 + il];
        a0 += (bflo(u0.x) + bflo(u1.x)) + (bflo(u2.x) + bflo(u3.x));
        a1 += (bfhi(u0.x) + bfhi(u1.x)) + (bfhi(u2.x) + bfhi(u3.x));
        a2 += (bflo(u0.y) + bflo(u1.y)) + (bflo(u2.y) + bflo(u3.y));
        a3 += (bfhi(u0.y) + bfhi(u1.y)) + (bfhi(u2.y) + bfhi(u3.y));
        a4 += (bflo(u0.z) + bflo(u1.z)) + (bflo(u2.z) + bflo(u3.z));
        a5 += (bfhi(u0.z) + bfhi(u1.z)) + (bfhi(u2.z) + bfhi(u3.z));
        a6 += (bflo(u0.w) + bflo(u1.w)) + (bflo(u2.w) + bflo(u3.w));
        a7 += (bfhi(u0.w) + bfhi(u1.w)) + (bfhi(u2.w) + bfhi(u3.w));
    }
    for (; p < end; ++p) {
        uint4 uu = x4[(size_t)srcs[p] * 16 + il];
        a0 += bflo(uu.x); a1 += bfhi(uu.x);
        a2 += bflo(uu.y); a3 += bfhi(uu.y);
        a4 += bflo(uu.z); a5 += bfhi(uu.z);
        a6 += bflo(uu.w); a7 += bfhi(uu.w);
    }
    a0 += b0; a1 += b1; a2 += b2; a3 += b3;
    a4 += b4; a5 += b5; a6 += b6; a7 += b7;
    uint4 o;
    o.x = f2bfu(a0) | (f2bfu(a1) << 16);
    o.y = f2bfu(a2) | (f2bfu(a3) << 16);
    o.z = f2bfu(a4) | (f2bfu(a5) << 16);
    o.w = f2bfu(a6) | (f2bfu(a7) << 16);
    y4[(size_t)w * 16 + il] = o;
}

// ---------------- GEMM1: K=128 MFMA, LDS-staged A, LDS-packed coalesced C-write, atomic stats ----------------
__global__ __launch_bounds__(256) void k_gemm_s1(const unsigned short* __restrict__ in,
        const short* __restrict__ WT, const float* __restrict__ bias,
        unsigned short* __restrict__ out, float* __restrict__ gstat) {
    __shared__ __align__(16) short Al[64 * 136];
    __shared__ float lsum[HH], lsq[HH];
    int tid = threadIdx.x;
    if (tid < HH) { lsum[tid] = 0.f; lsq[tid] = 0.f; }
    int row0 = blockIdx.x * 64;
    {
        int r = tid >> 2;
        int k0 = (tid & 3) * 32;
        int grow = row0 + r;
        uint4* d4 = (uint4*)&Al[r * 136 + k0];
        if (grow < NN) {
            const uint4* s4 = (const uint4*)(in + (size_t)grow * HH + k0);
            d4[0] = s4[0]; d4[1] = s4[1]; d4[2] = s4[2]; d4[3] = s4[3];
        } else {
            uint4 z = {0, 0, 0, 0};
            d4[0] = z; d4[1] = z; d4[2] = z; d4[3] = z;
        }
    }
    __syncthreads();
    int wave = tid >> 6;
    int lane = tid & 63;
    int ln = lane & 15, quad = lane >> 4;
    int wcol0 = wave * 32;
    f32x4 acc[4][2];
    #pragma unroll
    for (int rt = 0; rt < 4; rt++)
        #pragma unroll
        for (int ct = 0; ct < 2; ct++) acc[rt][ct] = (f32x4){0.f, 0.f, 0.f, 0.f};
    #pragma unroll
    for (int ks = 0; ks < 4; ks++) {
        bf16x8 a[4], b[2];
        #pragma unroll
        for (int ct = 0; ct < 2; ct++)
            b[ct] = *(const bf16x8*)(WT + (size_t)(wcol0 + ct * 16 + ln) * HH + ks * 32 + quad * 8);
        #pragma unroll
        for (int rt = 0; rt < 4; rt++)
            a[rt] = *(const bf16x8*)(&Al[(rt * 16 + ln) * 136 + ks * 32 + quad * 8]);
        #pragma unroll
        for (int rt = 0; rt < 4; rt++)
            #pragma unroll
            for (int ct = 0; ct < 2; ct++)
                acc[rt][ct] = __builtin_amdgcn_mfma_f32_16x16x32_bf16(a[rt], b[ct], acc[rt][ct], 0, 0, 0);
    }
    float b0 = bias[wcol0 + ln];
    float b1 = bias[wcol0 + 16 + ln];
    __syncthreads();   // all MFMA reads of Al complete before overwrite
    float s[2] = {0.f, 0.f}, s2[2] = {0.f, 0.f};
    #pragma unroll
    for (int rt = 0; rt < 4; rt++) {
        #pragma unroll
        for (int r = 0; r < 4; r++) {
            int lrow = rt * 16 + quad * 4 + r;
            float hv0 = acc[rt][0][r] + b0;
            float hv1 = acc[rt][1][r] + b1;
            Al[lrow * 136 + wcol0 + ln] = (short)f2bfu(hv0);
            Al[lrow * 136 + wcol0 + 16 + ln] = (short)f2bfu(hv1);
            if (row0 + lrow < NN) {
                s[0] += hv0; s2[0] = fmaf(hv0, hv0, s2[0]);
                s[1] += hv1; s2[1] = fmaf(hv1, hv1, s2[1]);
            }
        }
    }
    atomicAdd(&lsum[wcol0 + ln], s[0]);
    atomicAdd(&lsum[wcol0 + 16 + ln], s[1]);
    atomicAdd(&lsq[wcol0 + ln], s2[0]);
    atomicAdd(&lsq[wcol0 + 16 + ln], s2[1]);
    __syncthreads();
    {   // coalesced store: thread = (row, 32-col chunk), 4 x uint4
        int r = tid >> 2, c0 = (tid & 3) * 32;
        int grow = row0 + r;
        if (grow < NN) {
            const uint4* srcp = (const uint4*)&Al[r * 136 + c0];
            uint4* dstp = (uint4*)(out + (size_t)grow * HH + c0);
            dstp[0] = srcp[0]; dstp[1] = srcp[1]; dstp[2] = srcp[2]; dstp[3] = srcp[3];
        }
    }
    if (tid < HH) {
        int sl = (blockIdx.x & (STSLOT - 1)) << 8;
        atomicAdd(&gstat[sl + tid], lsum[tid]);
        atomicAdd(&gstat[sl + 128 + tid], lsq[tid]);
    }
}

// ---------------- GEMM2: BN affine + ReLU on load, ELU out, LDS-packed coalesced C-write ----------------
__global__ __launch_bounds__(256) void k_gemm_bn(const unsigned short* __restrict__ in,
        const short* __restrict__ WT, const float* __restrict__ bias,
        const float* __restrict__ gstat, const float* __restrict__ gm, const float* __restrict__ bt,
        unsigned short* __restrict__ out) {
    __shared__ __align__(16) short Al[64 * 136];
    __shared__ __align__(16) float bnsc[HH], bnsh[HH];
    int tid = threadIdx.x;
    if (tid < HH) {
        float s = 0.f, s2 = 0.f;
        #pragma unroll
        for (int k = 0; k < STSLOT; ++k) {
            s += gstat[(k << 8) + tid];
            s2 += gstat[(k << 8) + 128 + tid];
        }
        float mu = s * (1.f / NN);
        float var = fmaxf(s2 * (1.f / NN) - mu * mu, 0.f);
        float a = gm[tid] * rsqrtf(var + BN_EPS);
        bnsc[tid] = a;
        bnsh[tid] = fmaf(-mu, a, bt[tid]);
    }
    __syncthreads();
    int row0 = blockIdx.x * 64;
    {
        int r = tid >> 2;
        int k0 = (tid & 3) * 32;
        int grow = row0 + r;
        short* dst = &Al[r * 136 + k0];
        if (grow < NN) {
            const uint4* s4 = (const uint4*)(in + (size_t)grow * HH + k0);
            unsigned* d = (unsigned*)dst;
            #pragma unroll
            for (int q = 0; q < 4; q++) {
                uint4 u = s4[q];
                float4 sc0 = *(const float4*)(bnsc + k0 + q * 8);
                float4 sh0 = *(const float4*)(bnsh + k0 + q * 8);
                float4 sc1 = *(const float4*)(bnsc + k0 + q * 8 + 4);
                float4 sh1 = *(const float4*)(bnsh + k0 + q * 8 + 4);
                float a0 = bflo(u.x), a1 = bfhi(u.x);
                float a2 = bflo(u.y), a3 = bfhi(u.y);
                float a4 = bflo(u.z), a5 = bfhi(u.z);
                float a6 = bflo(u.w), a7 = bfhi(u.w);
                a0 = fmaxf(fmaf(a0, sc0.x, sh0.x), 0.f);
                a1 = fmaxf(fmaf(a1, sc0.y, sh0.y), 0.f);
                a2 = fmaxf(fmaf(a2, sc0.z, sh0.z), 0.f);
                a3 = fmaxf(fmaf(a3, sc0.w, sh0.w), 0.f);
                a4 = fmaxf(fmaf(a4, sc1.x, sh1.x), 0.f);
                a5 = fmaxf(fmaf(a5, sc1.y, sh1.y), 0.f);
                a6 = fmaxf(fmaf(a6, sc1.z, sh1.z), 0.f);
                a7 = fmaxf(fmaf(a7, sc1.w, sh1.w), 0.f);
                d[q * 4 + 0] = f2bfu(a0) | (f2bfu(a1) << 16);
                d[q * 4 + 1] = f2bfu(a2) | (f2bfu(a3) << 16);
                d[q * 4 + 2] = f2bfu(a4) | (f2bfu(a5) << 16);
                d[q * 4 + 3] = f2bfu(a6) | (f2bfu(a7) << 16);
            }
        } else {
            uint4 z = {0, 0, 0, 0};
            uint4* d4 = (uint4*)dst;
            d4[0] = z; d4[1] = z; d4[2] = z; d4[3] = z;
        }
    }
    __syncthreads();
    int wave = tid >> 6;
    int lane = tid & 63;
    int ln = lane & 15, quad = lane >> 4;
    int wcol0 = wave * 32;
    f32x4 acc[4][2];
    #pragma unroll
    for (int rt = 0; rt < 4; rt++)
        #pragma unroll
        for (int ct = 0; ct < 2; ct++) acc[rt][ct] = (f32x4){0.f, 0.f, 0.f, 0.f};
    #pragma unroll
    for (int ks = 0; ks < 4; ks++) {
        bf16x8 a[4], b[2];
        #pragma unroll
        for (int ct = 0; ct < 2; ct++)
            b[ct] = *(const bf16x8*)(WT + (size_t)(wcol0 + ct * 16 + ln) * HH + ks * 32 + quad * 8);
        #pragma unroll
        for (int rt = 0; rt < 4; rt++)
            a[rt] = *(const bf16x8*)(&Al[(rt * 16 + ln) * 136 + ks * 32 + quad * 8]);
        #pragma unroll
        for (int rt = 0; rt < 4; rt++)
            #pragma unroll
            for (int ct = 0; ct < 2; ct++)
                acc[rt][ct] = __builtin_amdgcn_mfma_f32_16x16x32_bf16(a[rt], b[ct], acc[rt][ct], 0, 0, 0);
    }
    float b0 = bias[wcol0 + ln];
    float b1 = bias[wcol0 + 16 + ln];
    __syncthreads();   // all MFMA reads of Al complete before overwrite
    #pragma unroll
    for (int rt = 0; rt < 4; rt++) {
        #pragma unroll
        for (int r = 0; r < 4; r++) {
            int lrow = rt * 16 + quad * 4 + r;
            float hv0 = elu01f(acc[rt][0][r] + b0);
            float hv1 = elu01f(acc[rt][1][r] + b1);
            Al[lrow * 136 + wcol0 + ln] = (short)f2bfu(hv0);
            Al[lrow * 136 + wcol0 + 16 + ln] = (short)f2bfu(hv1);
        }
    }
    __syncthreads();
    {   // coalesced store: thread = (row, 32-col chunk), 4 x uint4
        int r = tid >> 2, c0 = (tid & 3) * 32;
        int grow = row0 + r;
        if (grow < NN) {
            const uint4* srcp = (const uint4*)&Al[r * 136 + c0];
            uint4* dstp = (uint4*)(out + (size_t)grow * HH + c0);
            dstp[0] = srcp[0]; dstp[1] = srcp[1]; dstp[2] = srcp[2]; dstp[3] = srcp[3];
        }
    }
}

// ---------------- pooling (bf16 input) ----------------
__global__ __launch_bounds__(128) void k_pool_part(const unsigned short* __restrict__ x,
                                                   const int* __restrict__ gptr,
                                                   float* __restrict__ psum, float* __restrict__ pmax) {
    int g = blockIdx.x >> 4;
    int ch = blockIdx.x & 15;
    int s = gptr[g], e = gptr[g + 1];
    int len = e - s;
    int per = (len + PCH - 1) / PCH;
    int lo = s + ch * per;
    int hi = min(lo + per, e);
    int c = threadIdx.x;
    float sm = 0.f, mx = -INFINITY;
    for (int i = lo; i < hi; ++i) {
        float v = bfu2f(x[(size_t)i * HH + c]);
        sm += v; mx = fmaxf(mx, v);
    }
    psum[(size_t)blockIdx.x * HH + c] = sm;
    pmax[(size_t)blockIdx.x * HH + c] = mx;
}

// pool finalize + classifier layer 1 fused (one block per graph)
__global__ __launch_bounds__(128) void k_pool_cls1(const float* __restrict__ psum, const float* __restrict__ pmax,
                                                   const int* __restrict__ gptr, const float* __restrict__ g0,
                                                   const float* __restrict__ cw1, const float* __restrict__ cb1,
                                                   float* __restrict__ z1) {
    __shared__ float zr[264];
    int g = blockIdx.x, c = threadIdx.x;
    float sm = 0.f, mx = -INFINITY;
    for (int ch = 0; ch < PCH; ++ch) {
        sm += psum[(size_t)(g * PCH + ch) * HH + c];
        mx = fmaxf(mx, pmax[(size_t)(g * PCH + ch) * HH + c]);
    }
    int cntn = gptr[g + 1] - gptr[g];
    zr[c] = sm / (float)max(cntn, 1);
    zr[128 + c] = mx;
    if (c < GG) zr[256 + c] = g0[g * GG + c];
    __syncthreads();
    float acc = cb1[c];
    for (int k = 0; k < 264; ++k) acc = fmaf(zr[k], cw1[k * HH + c], acc);
    z1[g * HH + c] = elu01f(acc);
}

__global__ __launch_bounds__(128) void k_cls2(const float* __restrict__ z1, const float* __restrict__ cgm,
                                              const float* __restrict__ cbt, const float* __restrict__ cw2,
                                              const float* __restrict__ cb2, float* __restrict__ outp) {
    __shared__ float zn[HH * 65];
    int c = threadIdx.x;
    float s = 0.f, s2 = 0.f;
    for (int g = 0; g < BB; ++g) {
        float v = z1[g * HH + c];
        s += v; s2 = fmaf(v, v, s2);
    }
    float mu = s * (1.f / BB);
    float var = fmaxf(s2 * (1.f / BB) - mu * mu, 0.f);
    float a = cgm[c] * rsqrtf(var + BN_EPS);
    float sh = fmaf(-mu, a, cbt[c]);
    for (int g = 0; g < BB; ++g) zn[c * 65 + g] = fmaf(z1[g * HH + c], a, sh);
    __syncthreads();
    if (c < BB) {
        float l0 = cb2[0], l1 = cb2[1];
        for (int k = 0; k < HH; ++k) {
            float v = zn[k * 65 + c];
            l0 = fmaf(v, cw2[k * 2 + 0], l0);
            l1 = fmaf(v, cw2[k * 2 + 1], l1);
        }
        float m = fmaxf(l0, l1);
        float e0 = __expf(l0 - m), e1 = __expf(l1 - m);
        float inv = 1.f / (e0 + e1);
        outp[c * 2 + 0] = e0 * inv;
        outp[c * 2 + 1] = e1 * inv;
    }
}

extern "C" void kernel_launch(void* const* d_in, const int* in_sizes, int n_in,
                              void* d_out, int out_size, void* d_ws, size_t ws_size,
                              hipStream_t stream) {
    (void)in_sizes; (void)n_in; (void)out_size; (void)ws_size;
    const float* h0     = (const float*)d_in[0];
    const float* coord0 = (const float*)d_in[1];
    const float* g0     = (const float*)d_in[2];
    const int*   eidx   = (const int*)d_in[3];
    const int*   batch  = (const int*)d_in[4];
    const float* w1_0   = (const float*)d_in[5];
    const float* b1_0   = (const float*)d_in[6];
    const float* gm_0   = (const float*)d_in[7];
    const float* bt_0   = (const float*)d_in[8];
    const float* w2_0   = (const float*)d_in[9];
    const float* b2_0   = (const float*)d_in[10];
    const float* w1_r   = (const float*)d_in[11];
    const float* b1_r   = (const float*)d_in[12];
    const float* gm_r   = (const float*)d_in[13];
    const float* bt_r   = (const float*)d_in[14];
    const float* w2_r   = (const float*)d_in[15];
    const float* b2_r   = (const float*)d_in[16];
    const float* cw1    = (const float*)d_in[17];
    const float* cb1    = (const float*)d_in[18];
    const float* cgm    = (const float*)d_in[19];
    const float* cbt    = (const float*)d_in[20];
    const float* cw2    = (const float*)d_in[21];
    const float* cb2    = (const float*)d_in[22];
    float* outp = (float*)d_out;

    const int* esrc = eidx;
    const int* edst = eidx + EE;

    char* p = (char*)d_ws;
    auto alloc = [&](size_t bytes) { void* r = (void*)p; p += (bytes + 255) & ~(size_t)255; return r; };
    int*            bincnt   = (int*)alloc((size_t)NBINS * 4);                 // }
    float*          gstat    = (float*)alloc((size_t)3 * STSLOT * 256 * 4);    // } one memset region
    unsigned short* x0bf     = (unsigned short*)alloc((size_t)NN * 32 * 2);    // [NN][32] bf16
    float*          y19f     = (float*)alloc((size_t)NN * 32 * 4);             // [NN][32] f32
    unsigned short* hbf      = (unsigned short*)alloc((size_t)NN * HH * 2);
    unsigned*       xbf      = (unsigned*)alloc((size_t)NN * 64 * 4);
    unsigned*       ybf      = (unsigned*)alloc((size_t)NN * 64 * 4);
    int*            rp       = (int*)alloc((size_t)(NN + 1) * 4);
    int*            srcs     = (int*)alloc((size_t)EE * 4);
    int*            gptr     = (int*)alloc((BB + 1) * 4);
    short*          wt       = (short*)alloc((size_t)5 * HH * HH * 2);
    float*          psum     = (float*)alloc((size_t)BB * PCH * HH * 4);
    float*          pmax     = (float*)alloc((size_t)BB * PCH * HH * 4);
    float*          z1b      = (float*)alloc((size_t)BB * HH * 4);
    uint2*          binbuf   = (uint2*)alloc((size_t)NBINS * BCAP * 8);        // 25.7 MB, own region

    const int NB_A = (EE + ACH - 1) / ACH;          // 782
    const int NB_AGG = (NN * 64 + 255) / 256;       // 25000 (wave per node, layer 0)
    const int NB_AGG4 = (NN + 15) / 16;             // 6250  (4 nodes per wave, layers 1..2)
    const int NB_G32 = NN / 32;                     // 3125
    const int NB_G64 = (NN + 63) / 64;              // 1563

    size_t zlen = (size_t)((char*)x0bf - (char*)bincnt);   // bincnt + all gstat buffers
    hipMemsetAsync(bincnt, 0, zlen, stream);

    // CSR build (LDS counting sort, 512 threads) + weight prep + feature build + gptr
    k_binA<<<NB_A, 512, 0, stream>>>(esrc, edst, bincnt, binbuf);
    k_binB<<<NBINS, 512, 0, stream>>>(binbuf, bincnt, rp, srcs);
    k_prep<<<NB_WP + NB_X0, 256, 0, stream>>>(w2_0, w1_r, w2_r, wt, h0, coord0, x0bf, batch, gptr);

    // layer 0: split agg (wave/node) -> f32 y19 -> K=19 GEMM (stats) -> GEMM2 (BN from raw stats)
    k_agg_small<<<NB_AGG, 256, 0, stream>>>((const uint4*)x0bf, rp, srcs, y19f);
    k_gemm_small<K0><<<NB_G32, 256, 0, stream>>>(y19f, w1_0, b1_0, hbf, gstat);
    k_gemm_bn<<<NB_G64, 256, 0, stream>>>(hbf, wt, b2_0, gstat, gm_0, bt_0, (unsigned short*)xbf);

    // layers 1..2: grouped agg (4 nodes/wave) + MFMA GEMM with atomic stats
    for (int i = 0; i < 2; ++i) {
        float* gs = gstat + (size_t)(1 + i) * STSLOT * 256;
        k_agg128_bf<<<NB_AGG4, 256, 0, stream>>>((const uint4*)xbf, rp, srcs, (uint4*)ybf);
        k_gemm_s1<<<NB_G64, 256, 0, stream>>>((const unsigned short*)ybf,
                wt + (size_t)(1 + i) * HH * HH, b1_r + i * HH, hbf, gs);
        k_gemm_bn<<<NB_G64, 256, 0, stream>>>(hbf, wt + (size_t)(3 + i) * HH * HH, b2_r + i * HH,
                                              gs, gm_r + i * HH, bt_r + i * HH, (unsigned short*)xbf);
    }

    // pooling + classifier
    k_pool_part<<<BB * PCH, 128, 0, stream>>>((const unsigned short*)xbf, gptr, psum, pmax);
    k_pool_cls1<<<BB, 128, 0, stream>>>(psum, pmax, gptr, g0, cw1, cb1, z1b);
    k_cls2<<<1, 128, 0, stream>>>(z1b, cgm, cbt, cw2, cb2, outp);
}

// Round 13
// 473.090 us; speedup vs baseline: 1.0772x; 1.0231x over previous
//
#include <hip/hip_runtime.h>
#include <math.h>

#define NN 100000
#define EE 1600000
#define BB 64
#define FF 16
#define HH 128
#define GG 8
#define K0 19
#define BN_EPS 1e-5f
#define PCH 16
#define BSHIFT 8
#define BNODES 256
#define NBINS 391          // ceil(NN/256)
#define BCAP 8192
#define ACH 2048           // edges per phase-A block
#define NB_WP 320          // (5*HH*HH+255)/256
#define NB_X0 12500        // NN*32/256
#define STSLOT 8           // atomic-stat shadow copies

typedef short bf16x8 __attribute__((ext_vector_type(8)));
typedef float f32x4 __attribute__((ext_vector_type(4)));

__device__ __forceinline__ float elu01f(float v) {
    return v > 0.f ? v : 0.1f * (__expf(v) - 1.f);
}

__device__ __forceinline__ unsigned f2bfu(float f) {
    unsigned u = __float_as_uint(f);
    unsigned r = u + 0x7FFFu + ((u >> 16) & 1u);
    return r >> 16;
}
__device__ __forceinline__ short f2bf(float f) { return (short)f2bfu(f); }
__device__ __forceinline__ float bfu2f(unsigned short b) {
    return __uint_as_float(((unsigned)b) << 16);
}
__device__ __forceinline__ float bflo(unsigned u) { return __uint_as_float(u << 16); }
__device__ __forceinline__ float bfhi(unsigned u) { return __uint_as_float(u & 0xffff0000u); }

// ---------------- CSR build: 2-phase LDS counting sort (512 threads) ----------------
__global__ __launch_bounds__(512) void k_binA(const int* __restrict__ esrc, const int* __restrict__ edst,
                                              int* __restrict__ bincnt, uint2* __restrict__ binbuf) {
    __shared__ int hist[NBINS];
    __shared__ int gbase[NBINS];
    __shared__ int cur[NBINS];
    __shared__ int sc[512];
    __shared__ uint2 ebuf[ACH];
    __shared__ uint2 sorted[ACH];
    int tid = threadIdx.x;
    int e0 = blockIdx.x * ACH;
    int n = min(ACH, EE - e0);
    if (tid < NBINS) hist[tid] = 0;
    __syncthreads();
    for (int i = tid; i < n; i += 512) {
        int s = esrc[e0 + i];
        int d = edst[e0 + i];
        ebuf[i] = make_uint2((unsigned)s, (unsigned)d);
        atomicAdd(&hist[d >> BSHIFT], 1);
    }
    __syncthreads();
    sc[tid] = (tid < NBINS) ? hist[tid] : 0;
    __syncthreads();
    for (int off = 1; off < 512; off <<= 1) {
        int v = (tid >= off) ? sc[tid - off] : 0;
        __syncthreads();
        sc[tid] += v;
        __syncthreads();
    }
    if (tid < NBINS) {
        int c = hist[tid];
        gbase[tid] = (c > 0) ? atomicAdd(&bincnt[tid], c) : 0;
        cur[tid] = (tid > 0) ? sc[tid - 1] : 0;
    }
    __syncthreads();
    for (int i = tid; i < n; i += 512) {
        uint2 e = ebuf[i];
        int b = (int)(e.y >> BSHIFT);
        int pos = atomicAdd(&cur[b], 1);
        sorted[pos] = e;
    }
    __syncthreads();
    for (int i = tid; i < n; i += 512) {
        uint2 e = sorted[i];
        int b = (int)(e.y >> BSHIFT);
        int ls = (b > 0) ? sc[b - 1] : 0;
        int gpos = gbase[b] + (i - ls);
        binbuf[(size_t)b * BCAP + gpos] = e;
    }
}

// phase B: per-bin counting sort; block computes its own global base from bincnt (512 threads)
__global__ __launch_bounds__(512) void k_binB(const uint2* __restrict__ binbuf, const int* __restrict__ bincnt,
                                              int* __restrict__ rp, int* __restrict__ srcs) {
    __shared__ int hist[BNODES];
    __shared__ int scx[BNODES];
    __shared__ int scur[BNODES];
    __shared__ int rsum[512];
    __shared__ int sbuf[BCAP];
    int b = blockIdx.x;
    int n = bincnt[b];
    int tid = threadIdx.x;
    // base = sum bincnt[0..b-1]
    rsum[tid] = (tid < b) ? bincnt[tid] : 0;
    if (tid < BNODES) hist[tid] = 0;
    __syncthreads();
    for (int off = 256; off > 0; off >>= 1) {
        if (tid < off) rsum[tid] += rsum[tid + off];
        __syncthreads();
    }
    int base = rsum[0];
    const uint2* eb = binbuf + (size_t)b * BCAP;
    for (int i = tid; i < n; i += 512)
        atomicAdd(&hist[eb[i].y & (BNODES - 1)], 1);
    __syncthreads();
    if (tid < BNODES) scx[tid] = hist[tid];
    __syncthreads();
    for (int off = 1; off < BNODES; off <<= 1) {
        int vv = (tid >= off && tid < BNODES) ? scx[tid - off] : 0;
        __syncthreads();
        if (tid < BNODES) scx[tid] += vv;
        __syncthreads();
    }
    if (tid < BNODES) {
        int excl = (tid > 0) ? scx[tid - 1] : 0;
        int node = (b << BSHIFT) + tid;
        if (node < NN) rp[node] = base + excl;
        scur[tid] = excl;
    }
    if (b == NBINS - 1 && tid == 0) rp[NN] = EE;
    __syncthreads();
    for (int i = tid; i < n; i += 512) {
        uint2 e = eb[i];
        int pos = atomicAdd(&scur[e.y & (BNODES - 1)], 1);
        sbuf[pos] = (int)e.x;
    }
    __syncthreads();
    for (int i = tid; i < n; i += 512) srcs[base + i] = sbuf[i];
}

// ---------------- merged prep: weight transpose + x0 feature build + gptr search ----------------
__global__ __launch_bounds__(256) void k_prep(const float* __restrict__ w2_0, const float* __restrict__ w1_r,
                                              const float* __restrict__ w2_r, short* __restrict__ wt,
                                              const float* __restrict__ h0, const float* __restrict__ coord,
                                              unsigned short* __restrict__ x0,
                                              const int* __restrict__ batch, int* __restrict__ gptr) {
    int b = blockIdx.x;
    int tid = threadIdx.x;
    if (b == 0 && tid <= BB) {
        int t = tid;
        int lo = 0, hi = NN;
        while (lo < hi) { int mid = (lo + hi) >> 1; if (batch[mid] < t) lo = mid + 1; else hi = mid; }
        gptr[t] = lo;
    }
    if (b < NB_WP) {
        int t = b * 256 + tid;
        if (t >= 5 * HH * HH) return;
        int m = t >> 14;
        int rem = t & 16383;
        int col = rem >> 7;
        int k = rem & 127;
        const float* src = (m == 0) ? w2_0 : (m <= 2 ? w1_r + (size_t)(m - 1) * HH * HH
                                                     : w2_r + (size_t)(m - 3) * HH * HH);
        wt[t] = f2bf(src[k * HH + col]);
    } else {
        int i = (b - NB_WP) * 256 + tid;
        if (i >= NN * 32) return;
        int node = i >> 5, k = i & 31;
        float v = 0.f;
        if (k < FF) v = h0[node * FF + k];
        else if (k < K0) v = coord[node * 3 + (k - FF)];
        x0[i] = (unsigned short)f2bfu(v);
    }
}

// ---------------- layer-0 aggregation v2: 16 nodes/wave, 4-lane group owns a node ----------------
// One dwordx4 gather moves 16 edges' slices (1 KB); 8-deep unroll = 8 KB in flight per wave;
// no cross-lane reduction (group exclusively owns its node).
__global__ __launch_bounds__(256) void k_agg_small(const uint4* __restrict__ x, const int* __restrict__ rp,
                                                   const int* __restrict__ srcs, float* __restrict__ y) {
    int wave = (blockIdx.x * 256 + threadIdx.x) >> 6;
    int lane = threadIdx.x & 63;
    int g = lane >> 2, il = lane & 3;
    int w = wave * 16 + g;
    if (w >= NN) return;
    int beg = rp[w], end = rp[w + 1];
    uint4 u = x[(size_t)w * 4 + il];
    float a0 = bflo(u.x), a1 = bfhi(u.x), a2 = bflo(u.y), a3 = bfhi(u.y);
    float a4 = bflo(u.z), a5 = bfhi(u.z), a6 = bflo(u.w), a7 = bfhi(u.w);
    float b0 = 0.f, b1 = 0.f, b2 = 0.f, b3 = 0.f, b4 = 0.f, b5 = 0.f, b6 = 0.f, b7 = 0.f;
    int p = beg;
    for (; p + 8 <= end; p += 8) {
        int s0 = srcs[p + 0], s1 = srcs[p + 1], s2 = srcs[p + 2], s3 = srcs[p + 3];
        int s4 = srcs[p + 4], s5 = srcs[p + 5], s6 = srcs[p + 6], s7 = srcs[p + 7];
        uint4 u0 = x[(size_t)s0 * 4 + il];
        uint4 u1 = x[(size_t)s1 * 4 + il];
        uint4 u2 = x[(size_t)s2 * 4 + il];
        uint4 u3 = x[(size_t)s3 * 4 + il];
        uint4 u4 = x[(size_t)s4 * 4 + il];
        uint4 u5 = x[(size_t)s5 * 4 + il];
        uint4 u6 = x[(size_t)s6 * 4 + il];
        uint4 u7 = x[(size_t)s7 * 4 + il];
        a0 += (bflo(u0.x) + bflo(u1.x)) + (bflo(u2.x) + bflo(u3.x));
        a1 += (bfhi(u0.x) + bfhi(u1.x)) + (bfhi(u2.x) + bfhi(u3.x));
        a2 += (bflo(u0.y) + bflo(u1.y)) + (bflo(u2.y) + bflo(u3.y));
        a3 += (bfhi(u0.y) + bfhi(u1.y)) + (bfhi(u2.y) + bfhi(u3.y));
        a4 += (bflo(u0.z) + bflo(u1.z)) + (bflo(u2.z) + bflo(u3.z));
        a5 += (bfhi(u0.z) + bfhi(u1.z)) + (bfhi(u2.z) + bfhi(u3.z));
        a6 += (bflo(u0.w) + bflo(u1.w)) + (bflo(u2.w) + bflo(u3.w));
        a7 += (bfhi(u0.w) + bfhi(u1.w)) + (bfhi(u2.w) + bfhi(u3.w));
        b0 += (bflo(u4.x) + bflo(u5.x)) + (bflo(u6.x) + bflo(u7.x));
        b1 += (bfhi(u4.x) + bfhi(u5.x)) + (bfhi(u6.x) + bfhi(u7.x));
        b2 += (bflo(u4.y) + bflo(u5.y)) + (bflo(u6.y) + bflo(u7.y));
        b3 += (bfhi(u4.y) + bfhi(u5.y)) + (bfhi(u6.y) + bfhi(u7.y));
        b4 += (bflo(u4.z) + bflo(u5.z)) + (bflo(u6.z) + bflo(u7.z));
        b5 += (bfhi(u4.z) + bfhi(u5.z)) + (bfhi(u6.z) + bfhi(u7.z));
        b6 += (bflo(u4.w) + bflo(u5.w)) + (bflo(u6.w) + bflo(u7.w));
        b7 += (bfhi(u4.w) + bfhi(u5.w)) + (bfhi(u6.w) + bfhi(u7.w));
    }
    for (; p < end; ++p) {
        uint4 uu = x[(size_t)srcs[p] * 4 + il];
        a0 += bflo(uu.x); a1 += bfhi(uu.x);
        a2 += bflo(uu.y); a3 += bfhi(uu.y);
        a4 += bflo(uu.z); a5 += bfhi(uu.z);
        a6 += bflo(uu.w); a7 += bfhi(uu.w);
    }
    a0 += b0; a1 += b1; a2 += b2; a3 += b3;
    a4 += b4; a5 += b5; a6 += b6; a7 += b7;
    float4* yo = (float4*)(y + (size_t)w * 32 + il * 8);
    yo[0] = make_float4(a0, a1, a2, a3);
    yo[1] = make_float4(a4, a5, a6, a7);
}

// ---------------- GEMM K=19 (fp32 in [NN][32], fp32 compute, bf16 out, atomic stats) ----------------
template<int K>
__global__ __launch_bounds__(256) void k_gemm_small(const float* __restrict__ in,
        const float* __restrict__ W, const float* __restrict__ bias,
        unsigned short* __restrict__ out, float* __restrict__ gstat) {
    constexpr int SK = ((K + 3) / 4) * 4 + 4;
    __shared__ __align__(16) float yt[32 * SK];
    __shared__ float red[256];
    int tid = threadIdx.x;
    int row0 = blockIdx.x * 32;
    for (int t = tid; t < 32 * SK; t += 256) {
        int r = t / SK, k = t - r * SK;
        float v = 0.f;
        if (k < K) v = in[(size_t)(row0 + r) * 32 + k];
        yt[t] = v;
    }
    __syncthreads();
    int col = tid & 127;
    int rg = tid >> 7;
    float acc[16];
    #pragma unroll
    for (int r = 0; r < 16; r++) acc[r] = 0.f;
    const float* ybase = &yt[rg * 16 * SK];
    int kk = 0;
    for (; kk + 4 <= K; kk += 4) {
        float w0 = W[(kk + 0) * HH + col];
        float w1 = W[(kk + 1) * HH + col];
        float w2 = W[(kk + 2) * HH + col];
        float w3 = W[(kk + 3) * HH + col];
        #pragma unroll
        for (int r = 0; r < 16; r++) {
            const float4 v = *(const float4*)&ybase[r * SK + kk];
            acc[r] = fmaf(v.x, w0, acc[r]);
            acc[r] = fmaf(v.y, w1, acc[r]);
            acc[r] = fmaf(v.z, w2, acc[r]);
            acc[r] = fmaf(v.w, w3, acc[r]);
        }
    }
    if constexpr (K % 4 != 0) {
        float w[4];
        #pragma unroll
        for (int j = 0; j < 4; j++) w[j] = (kk + j < K) ? W[(kk + j) * HH + col] : 0.f;
        #pragma unroll
        for (int r = 0; r < 16; r++) {
            const float4 v = *(const float4*)&ybase[r * SK + kk];
            acc[r] = fmaf(v.x, w[0], acc[r]);
            acc[r] = fmaf(v.y, w[1], acc[r]);
            acc[r] = fmaf(v.z, w[2], acc[r]);
            acc[r] = fmaf(v.w, w[3], acc[r]);
        }
    }
    float bcol = bias[col];
    float s = 0.f, s2 = 0.f;
    #pragma unroll
    for (int r = 0; r < 16; r++) {
        float hv = acc[r] + bcol;
        out[(size_t)(row0 + rg * 16 + r) * HH + col] = (unsigned short)f2bfu(hv);
        s += hv; s2 = fmaf(hv, hv, s2);
    }
    int sl = (blockIdx.x & (STSLOT - 1)) << 8;
    red[tid] = s; __syncthreads();
    if (tid < 128) atomicAdd(&gstat[sl + tid], s + red[tid + 128]);
    __syncthreads();
    red[tid] = s2; __syncthreads();
    if (tid < 128) atomicAdd(&gstat[sl + 128 + tid], s2 + red[tid + 128]);
}

// ---------------- bf16 aggregation v2: 4 nodes per wave, 16-lane group owns a node ----------------
__global__ __launch_bounds__(256) void k_agg128_bf(const uint4* __restrict__ x4, const int* __restrict__ rp,
                                                   const int* __restrict__ srcs, uint4* __restrict__ y4) {
    int wave = (blockIdx.x * 256 + threadIdx.x) >> 6;
    int lane = threadIdx.x & 63;
    int g = lane >> 4, il = lane & 15;
    int w = wave * 4 + g;
    if (w >= NN) return;
    int beg = rp[w], end = rp[w + 1];
    // self row: group loads its node's row (16 lanes x 16B)
    uint4 u = x4[(size_t)w * 16 + il];
    float a0 = bflo(u.x), a1 = bfhi(u.x), a2 = bflo(u.y), a3 = bfhi(u.y);
    float a4 = bflo(u.z), a5 = bfhi(u.z), a6 = bflo(u.w), a7 = bfhi(u.w);
    float b0 = 0.f, b1 = 0.f, b2 = 0.f, b3 = 0.f, b4 = 0.f, b5 = 0.f, b6 = 0.f, b7 = 0.f;
    int p = beg;
    for (; p + 8 <= end; p += 8) {
        int s0 = srcs[p + 0], s1 = srcs[p + 1], s2 = srcs[p + 2], s3 = srcs[p + 3];
        int s4 = srcs[p + 4], s5 = srcs[p + 5], s6 = srcs[p + 6], s7 = srcs[p + 7];
        uint4 u0 = x4[(size_t)s0 * 16 + il];
        uint4 u1 = x4[(size_t)s1 * 16 + il];
        uint4 u2 = x4[(size_t)s2 * 16 + il];
        uint4 u3 = x4[(size_t)s3 * 16 + il];
        uint4 u4 = x4[(size_t)s4 * 16 + il];
        uint4 u5 = x4[(size_t)s5 * 16 + il];
        uint4 u6 = x4[(size_t)s6 * 16 + il];
        uint4 u7 = x4[(size_t)s7 * 16 + il];
        a0 += (bflo(u0.x) + bflo(u1.x)) + (bflo(u2.x) + bflo(u3.x));
        a1 += (bfhi(u0.x) + bfhi(u1.x)) + (bfhi(u2.x) + bfhi(u3.x));
        a2 += (bflo(u0.y) + bflo(u1.y)) + (bflo(u2.y) + bflo(u3.y));
        a3 += (bfhi(u0.y) + bfhi(u1.y)) + (bfhi(u2.y) + bfhi(u3.y));
        a4 += (bflo(u0.z) + bflo(u1.z)) + (bflo(u2.z) + bflo(u3.z));
        a5 += (bfhi(u0.z) + bfhi(u1.z)) + (bfhi(u2.z) + bfhi(u3.z));
        a6 += (bflo(u0.w) + bflo(u1.w)) + (bflo(u2.w) + bflo(u3.w));
        a7 += (bfhi(u0.w) + bfhi(u1.w)) + (bfhi(u2.w) + bfhi(u3.w));
        b0 += (bflo(u4.x) + bflo(u5.x)) + (bflo(u6.x) + bflo(u7.x));
        b1 += (bfhi(u4.x) + bfhi(u5.x)) + (bfhi(u6.x) + bfhi(u7.x));
        b2 += (bflo(u4.y) + bflo(u5.y)) + (bflo(u6.y) + bflo(u7.y));
        b3 += (bfhi(u4.y) + bfhi(u5.y)) + (bfhi(u6.y) + bfhi(u7.y));
        b4 += (bflo(u4.z) + bflo(u5.z)) + (bflo(u6.z) + bflo(u7.z));
        b5 += (bfhi(u4.z) + bfhi(u5.z)) + (bfhi(u6.z) + bfhi(u7.z));
        b6 += (bflo(u4.w) + bflo(u5.w)) + (bflo(u6.w) + bflo(u7.w));
        b7 += (bfhi(u4.w) + bfhi(u5.w)) + (bfhi(u6.w) + bfhi(u7.w));
    }
    for (; p + 4 <= end; p += 4) {
        int s0 = srcs[p + 0], s1 = srcs[p + 1], s2 = srcs[p + 2], s3 = srcs[p + 3];
        uint4 u0 = x4[(size_t)s0 * 16 + il];
        uint4 u1 = x4[(size_t)s1 * 16 + il];
        uint4 u2 = x4[(size_t)s2 * 16 + il];
        uint4 u3 = x4[(size_t)s3 * 16 + il];
        a0 += (bflo(u0.x) + bflo(u1.x)) + (bflo(u2.x) + bflo(u3.x));
        a1 += (bfhi(u0.x) + bfhi(u1.x)) + (bfhi(u2.x) + bfhi(u3.x));
        a2 += (bflo(u0.y) + bflo(u1.y)) + (bflo(u2.y) + bflo(u3.y));
        a3 += (bfhi(u0.y) + bfhi(u1.y)) + (bfhi(u2.y) + bfhi(u3.y));
        a4 += (bflo(u0.z) + bflo(u1.z)) + (bflo(u2.z) + bflo(u3.z));
        a5 += (bfhi(u0.z) + bfhi(u1.z)) + (bfhi(u2.z) + bfhi(u3.z));
        a6 += (bflo(u0.w) + bflo(u1.w)) + (bflo(u2.w) + bflo(u3.w));
        a7 += (bfhi(u0.w) + bfhi(u1.w)) + (bfhi(u2.w) + bfhi(u3.w));
    }
    for (; p < end; ++p) {
        uint4 uu = x4[(size_t)srcs[p] * 16 + il];
        a0 += bflo(uu.x); a1 += bfhi(uu.x);
        a2 += bflo(uu.y); a3 += bfhi(uu.y);
        a4 += bflo(uu.z); a5 += bfhi(uu.z);
        a6 += bflo(uu.w); a7 += bfhi(uu.w);
    }
    a0 += b0; a1 += b1; a2 += b2; a3 += b3;
    a4 += b4; a5 += b5; a6 += b6; a7 += b7;
    uint4 o;
    o.x = f2bfu(a0) | (f2bfu(a1) << 16);
    o.y = f2bfu(a2) | (f2bfu(a3) << 16);
    o.z = f2bfu(a4) | (f2bfu(a5) << 16);
    o.w = f2bfu(a6) | (f2bfu(a7) << 16);
    y4[(size_t)w * 16 + il] = o;
}

// ---------------- GEMM1: K=128 MFMA, LDS-staged A, LDS-packed coalesced C-write, atomic stats ----------------
__global__ __launch_bounds__(256) void k_gemm_s1(const unsigned short* __restrict__ in,
        const short* __restrict__ WT, const float* __restrict__ bias,
        unsigned short* __restrict__ out, float* __restrict__ gstat) {
    __shared__ __align__(16) short Al[64 * 136];
    __shared__ float lsum[HH], lsq[HH];
    int tid = threadIdx.x;
    if (tid < HH) { lsum[tid] = 0.f; lsq[tid] = 0.f; }
    int row0 = blockIdx.x * 64;
    {
        int r = tid >> 2;
        int k0 = (tid & 3) * 32;
        int grow = row0 + r;
        uint4* d4 = (uint4*)&Al[r * 136 + k0];
        if (grow < NN) {
            const uint4* s4 = (const uint4*)(in + (size_t)grow * HH + k0);
            d4[0] = s4[0]; d4[1] = s4[1]; d4[2] = s4[2]; d4[3] = s4[3];
        } else {
            uint4 z = {0, 0, 0, 0};
            d4[0] = z; d4[1] = z; d4[2] = z; d4[3] = z;
        }
    }
    __syncthreads();
    int wave = tid >> 6;
    int lane = tid & 63;
    int ln = lane & 15, quad = lane >> 4;
    int wcol0 = wave * 32;
    f32x4 acc[4][2];
    #pragma unroll
    for (int rt = 0; rt < 4; rt++)
        #pragma unroll
        for (int ct = 0; ct < 2; ct++) acc[rt][ct] = (f32x4){0.f, 0.f, 0.f, 0.f};
    #pragma unroll
    for (int ks = 0; ks < 4; ks++) {
        bf16x8 a[4], b[2];
        #pragma unroll
        for (int ct = 0; ct < 2; ct++)
            b[ct] = *(const bf16x8*)(WT + (size_t)(wcol0 + ct * 16 + ln) * HH + ks * 32 + quad * 8);
        #pragma unroll
        for (int rt = 0; rt < 4; rt++)
            a[rt] = *(const bf16x8*)(&Al[(rt * 16 + ln) * 136 + ks * 32 + quad * 8]);
        #pragma unroll
        for (int rt = 0; rt < 4; rt++)
            #pragma unroll
            for (int ct = 0; ct < 2; ct++)
                acc[rt][ct] = __builtin_amdgcn_mfma_f32_16x16x32_bf16(a[rt], b[ct], acc[rt][ct], 0, 0, 0);
    }
    float b0 = bias[wcol0 + ln];
    float b1 = bias[wcol0 + 16 + ln];
    __syncthreads();   // all MFMA reads of Al complete before overwrite
    float s[2] = {0.f, 0.f}, s2[2] = {0.f, 0.f};
    #pragma unroll
    for (int rt = 0; rt < 4; rt++) {
        #pragma unroll
        for (int r = 0; r < 4; r++) {
            int lrow = rt * 16 + quad * 4 + r;
            float hv0 = acc[rt][0][r] + b0;
            float hv1 = acc[rt][1][r] + b1;
            Al[lrow * 136 + wcol0 + ln] = (short)f2bfu(hv0);
            Al[lrow * 136 + wcol0 + 16 + ln] = (short)f2bfu(hv1);
            if (row0 + lrow < NN) {
                s[0] += hv0; s2[0] = fmaf(hv0, hv0, s2[0]);
                s[1] += hv1; s2[1] = fmaf(hv1, hv1, s2[1]);
            }
        }
    }
    atomicAdd(&lsum[wcol0 + ln], s[0]);
    atomicAdd(&lsum[wcol0 + 16 + ln], s[1]);
    atomicAdd(&lsq[wcol0 + ln], s2[0]);
    atomicAdd(&lsq[wcol0 + 16 + ln], s2[1]);
    __syncthreads();
    {   // coalesced store: thread = (row, 32-col chunk), 4 x uint4
        int r = tid >> 2, c0 = (tid & 3) * 32;
        int grow = row0 + r;
        if (grow < NN) {
            const uint4* srcp = (const uint4*)&Al[r * 136 + c0];
            uint4* dstp = (uint4*)(out + (size_t)grow * HH + c0);
            dstp[0] = srcp[0]; dstp[1] = srcp[1]; dstp[2] = srcp[2]; dstp[3] = srcp[3];
        }
    }
    if (tid < HH) {
        int sl = (blockIdx.x & (STSLOT - 1)) << 8;
        atomicAdd(&gstat[sl + tid], lsum[tid]);
        atomicAdd(&gstat[sl + 128 + tid], lsq[tid]);
    }
}

// ---------------- GEMM2: BN affine + ReLU on load, ELU out, LDS-packed coalesced C-write ----------------
__global__ __launch_bounds__(256) void k_gemm_bn(const unsigned short* __restrict__ in,
        const short* __restrict__ WT, const float* __restrict__ bias,
        const float* __restrict__ gstat, const float* __restrict__ gm, const float* __restrict__ bt,
        unsigned short* __restrict__ out) {
    __shared__ __align__(16) short Al[64 * 136];
    __shared__ __align__(16) float bnsc[HH], bnsh[HH];
    int tid = threadIdx.x;
    if (tid < HH) {
        float s = 0.f, s2 = 0.f;
        #pragma unroll
        for (int k = 0; k < STSLOT; ++k) {
            s += gstat[(k << 8) + tid];
            s2 += gstat[(k << 8) + 128 + tid];
        }
        float mu = s * (1.f / NN);
        float var = fmaxf(s2 * (1.f / NN) - mu * mu, 0.f);
        float a = gm[tid] * rsqrtf(var + BN_EPS);
        bnsc[tid] = a;
        bnsh[tid] = fmaf(-mu, a, bt[tid]);
    }
    __syncthreads();
    int row0 = blockIdx.x * 64;
    {
        int r = tid >> 2;
        int k0 = (tid & 3) * 32;
        int grow = row0 + r;
        short* dst = &Al[r * 136 + k0];
        if (grow < NN) {
            const uint4* s4 = (const uint4*)(in + (size_t)grow * HH + k0);
            unsigned* d = (unsigned*)dst;
            #pragma unroll
            for (int q = 0; q < 4; q++) {
                uint4 u = s4[q];
                float4 sc0 = *(const float4*)(bnsc + k0 + q * 8);
                float4 sh0 = *(const float4*)(bnsh + k0 + q * 8);
                float4 sc1 = *(const float4*)(bnsc + k0 + q * 8 + 4);
                float4 sh1 = *(const float4*)(bnsh + k0 + q * 8 + 4);
                float a0 = bflo(u.x), a1 = bfhi(u.x);
                float a2 = bflo(u.y), a3 = bfhi(u.y);
                float a4 = bflo(u.z), a5 = bfhi(u.z);
                float a6 = bflo(u.w), a7 = bfhi(u.w);
                a0 = fmaxf(fmaf(a0, sc0.x, sh0.x), 0.f);
                a1 = fmaxf(fmaf(a1, sc0.y, sh0.y), 0.f);
                a2 = fmaxf(fmaf(a2, sc0.z, sh0.z), 0.f);
                a3 = fmaxf(fmaf(a3, sc0.w, sh0.w), 0.f);
                a4 = fmaxf(fmaf(a4, sc1.x, sh1.x), 0.f);
                a5 = fmaxf(fmaf(a5, sc1.y, sh1.y), 0.f);
                a6 = fmaxf(fmaf(a6, sc1.z, sh1.z), 0.f);
                a7 = fmaxf(fmaf(a7, sc1.w, sh1.w), 0.f);
                d[q * 4 + 0] = f2bfu(a0) | (f2bfu(a1) << 16);
                d[q * 4 + 1] = f2bfu(a2) | (f2bfu(a3) << 16);
                d[q * 4 + 2] = f2bfu(a4) | (f2bfu(a5) << 16);
                d[q * 4 + 3] = f2bfu(a6) | (f2bfu(a7) << 16);
            }
        } else {
            uint4 z = {0, 0, 0, 0};
            uint4* d4 = (uint4*)dst;
            d4[0] = z; d4[1] = z; d4[2] = z; d4[3] = z;
        }
    }
    __syncthreads();
    int wave = tid >> 6;
    int lane = tid & 63;
    int ln = lane & 15, quad = lane >> 4;
    int wcol0 = wave * 32;
    f32x4 acc[4][2];
    #pragma unroll
    for (int rt = 0; rt < 4; rt++)
        #pragma unroll
        for (int ct = 0; ct < 2; ct++) acc[rt][ct] = (f32x4){0.f, 0.f, 0.f, 0.f};
    #pragma unroll
    for (int ks = 0; ks < 4; ks++) {
        bf16x8 a[4], b[2];
        #pragma unroll
        for (int ct = 0; ct < 2; ct++)
            b[ct] = *(const bf16x8*)(WT + (size_t)(wcol0 + ct * 16 + ln) * HH + ks * 32 + quad * 8);
        #pragma unroll
        for (int rt = 0; rt < 4; rt++)
            a[rt] = *(const bf16x8*)(&Al[(rt * 16 + ln) * 136 + ks * 32 + quad * 8]);
        #pragma unroll
        for (int rt = 0; rt < 4; rt++)
            #pragma unroll
            for (int ct = 0; ct < 2; ct++)
                acc[rt][ct] = __builtin_amdgcn_mfma_f32_16x16x32_bf16(a[rt], b[ct], acc[rt][ct], 0, 0, 0);
    }
    float b0 = bias[wcol0 + ln];
    float b1 = bias[wcol0 + 16 + ln];
    __syncthreads();   // all MFMA reads of Al complete before overwrite
    #pragma unroll
    for (int rt = 0; rt < 4; rt++) {
        #pragma unroll
        for (int r = 0; r < 4; r++) {
            int lrow = rt * 16 + quad * 4 + r;
            float hv0 = elu01f(acc[rt][0][r] + b0);
            float hv1 = elu01f(acc[rt][1][r] + b1);
            Al[lrow * 136 + wcol0 + ln] = (short)f2bfu(hv0);
            Al[lrow * 136 + wcol0 + 16 + ln] = (short)f2bfu(hv1);
        }
    }
    __syncthreads();
    {   // coalesced store: thread = (row, 32-col chunk), 4 x uint4
        int r = tid >> 2, c0 = (tid & 3) * 32;
        int grow = row0 + r;
        if (grow < NN) {
            const uint4* srcp = (const uint4*)&Al[r * 136 + c0];
            uint4* dstp = (uint4*)(out + (size_t)grow * HH + c0);
            dstp[0] = srcp[0]; dstp[1] = srcp[1]; dstp[2] = srcp[2]; dstp[3] = srcp[3];
        }
    }
}

// ---------------- pooling (bf16 input) ----------------
__global__ __launch_bounds__(128) void k_pool_part(const unsigned short* __restrict__ x,
                                                   const int* __restrict__ gptr,
                                                   float* __restrict__ psum, float* __restrict__ pmax) {
    int g = blockIdx.x >> 4;
    int ch = blockIdx.x & 15;
    int s = gptr[g], e = gptr[g + 1];
    int len = e - s;
    int per = (len + PCH - 1) / PCH;
    int lo = s + ch * per;
    int hi = min(lo + per, e);
    int c = threadIdx.x;
    float sm = 0.f, mx = -INFINITY;
    for (int i = lo; i < hi; ++i) {
        float v = bfu2f(x[(size_t)i * HH + c]);
        sm += v; mx = fmaxf(mx, v);
    }
    psum[(size_t)blockIdx.x * HH + c] = sm;
    pmax[(size_t)blockIdx.x * HH + c] = mx;
}

// pool finalize + classifier layer 1 fused (one block per graph)
__global__ __launch_bounds__(128) void k_pool_cls1(const float* __restrict__ psum, const float* __restrict__ pmax,
                                                   const int* __restrict__ gptr, const float* __restrict__ g0,
                                                   const float* __restrict__ cw1, const float* __restrict__ cb1,
                                                   float* __restrict__ z1) {
    __shared__ float zr[264];
    int g = blockIdx.x, c = threadIdx.x;
    float sm = 0.f, mx = -INFINITY;
    for (int ch = 0; ch < PCH; ++ch) {
        sm += psum[(size_t)(g * PCH + ch) * HH + c];
        mx = fmaxf(mx, pmax[(size_t)(g * PCH + ch) * HH + c]);
    }
    int cntn = gptr[g + 1] - gptr[g];
    zr[c] = sm / (float)max(cntn, 1);
    zr[128 + c] = mx;
    if (c < GG) zr[256 + c] = g0[g * GG + c];
    __syncthreads();
    float acc = cb1[c];
    for (int k = 0; k < 264; ++k) acc = fmaf(zr[k], cw1[k * HH + c], acc);
    z1[g * HH + c] = elu01f(acc);
}

__global__ __launch_bounds__(128) void k_cls2(const float* __restrict__ z1, const float* __restrict__ cgm,
                                              const float* __restrict__ cbt, const float* __restrict__ cw2,
                                              const float* __restrict__ cb2, float* __restrict__ outp) {
    __shared__ float zn[HH * 65];
    int c = threadIdx.x;
    float s = 0.f, s2 = 0.f;
    for (int g = 0; g < BB; ++g) {
        float v = z1[g * HH + c];
        s += v; s2 = fmaf(v, v, s2);
    }
    float mu = s * (1.f / BB);
    float var = fmaxf(s2 * (1.f / BB) - mu * mu, 0.f);
    float a = cgm[c] * rsqrtf(var + BN_EPS);
    float sh = fmaf(-mu, a, cbt[c]);
    for (int g = 0; g < BB; ++g) zn[c * 65 + g] = fmaf(z1[g * HH + c], a, sh);
    __syncthreads();
    if (c < BB) {
        float l0 = cb2[0], l1 = cb2[1];
        for (int k = 0; k < HH; ++k) {
            float v = zn[k * 65 + c];
            l0 = fmaf(v, cw2[k * 2 + 0], l0);
            l1 = fmaf(v, cw2[k * 2 + 1], l1);
        }
        float m = fmaxf(l0, l1);
        float e0 = __expf(l0 - m), e1 = __expf(l1 - m);
        float inv = 1.f / (e0 + e1);
        outp[c * 2 + 0] = e0 * inv;
        outp[c * 2 + 1] = e1 * inv;
    }
}

extern "C" void kernel_launch(void* const* d_in, const int* in_sizes, int n_in,
                              void* d_out, int out_size, void* d_ws, size_t ws_size,
                              hipStream_t stream) {
    (void)in_sizes; (void)n_in; (void)out_size; (void)ws_size;
    const float* h0     = (const float*)d_in[0];
    const float* coord0 = (const float*)d_in[1];
    const float* g0     = (const float*)d_in[2];
    const int*   eidx   = (const int*)d_in[3];
    const int*   batch  = (const int*)d_in[4];
    const float* w1_0   = (const float*)d_in[5];
    const float* b1_0   = (const float*)d_in[6];
    const float* gm_0   = (const float*)d_in[7];
    const float* bt_0   = (const float*)d_in[8];
    const float* w2_0   = (const float*)d_in[9];
    const float* b2_0   = (const float*)d_in[10];
    const float* w1_r   = (const float*)d_in[11];
    const float* b1_r   = (const float*)d_in[12];
    const float* gm_r   = (const float*)d_in[13];
    const float* bt_r   = (const float*)d_in[14];
    const float* w2_r   = (const float*)d_in[15];
    const float* b2_r   = (const float*)d_in[16];
    const float* cw1    = (const float*)d_in[17];
    const float* cb1    = (const float*)d_in[18];
    const float* cgm    = (const float*)d_in[19];
    const float* cbt    = (const float*)d_in[20];
    const float* cw2    = (const float*)d_in[21];
    const float* cb2    = (const float*)d_in[22];
    float* outp = (float*)d_out;

    const int* esrc = eidx;
    const int* edst = eidx + EE;

    char* p = (char*)d_ws;
    auto alloc = [&](size_t bytes) { void* r = (void*)p; p += (bytes + 255) & ~(size_t)255; return r; };
    int*            bincnt   = (int*)alloc((size_t)NBINS * 4);                 // }
    float*          gstat    = (float*)alloc((size_t)3 * STSLOT * 256 * 4);    // } one memset region
    unsigned short* x0bf     = (unsigned short*)alloc((size_t)NN * 32 * 2);    // [NN][32] bf16
    float*          y19f     = (float*)alloc((size_t)NN * 32 * 4);             // [NN][32] f32
    unsigned short* hbf      = (unsigned short*)alloc((size_t)NN * HH * 2);
    unsigned*       xbf      = (unsigned*)alloc((size_t)NN * 64 * 4);
    unsigned*       ybf      = (unsigned*)alloc((size_t)NN * 64 * 4);
    int*            rp       = (int*)alloc((size_t)(NN + 1) * 4);
    int*            srcs     = (int*)alloc((size_t)EE * 4);
    int*            gptr     = (int*)alloc((BB + 1) * 4);
    short*          wt       = (short*)alloc((size_t)5 * HH * HH * 2);
    float*          psum     = (float*)alloc((size_t)BB * PCH * HH * 4);
    float*          pmax     = (float*)alloc((size_t)BB * PCH * HH * 4);
    float*          z1b      = (float*)alloc((size_t)BB * HH * 4);
    uint2*          binbuf   = (uint2*)alloc((size_t)NBINS * BCAP * 8);        // 25.7 MB, own region

    const int NB_A = (EE + ACH - 1) / ACH;          // 782
    const int NB_AGG16 = (NN + 63) / 64;            // 1563  (16 nodes/wave, layer 0)
    const int NB_AGG4 = (NN + 15) / 16;             // 6250  (4 nodes/wave, layers 1..2)
    const int NB_G32 = NN / 32;                     // 3125
    const int NB_G64 = (NN + 63) / 64;              // 1563

    size_t zlen = (size_t)((char*)x0bf - (char*)bincnt);   // bincnt + all gstat buffers
    hipMemsetAsync(bincnt, 0, zlen, stream);

    // CSR build (LDS counting sort, 512 threads) + weight prep + feature build + gptr
    k_binA<<<NB_A, 512, 0, stream>>>(esrc, edst, bincnt, binbuf);
    k_binB<<<NBINS, 512, 0, stream>>>(binbuf, bincnt, rp, srcs);
    k_prep<<<NB_WP + NB_X0, 256, 0, stream>>>(w2_0, w1_r, w2_r, wt, h0, coord0, x0bf, batch, gptr);

    // layer 0: grouped agg (16 nodes/wave) -> f32 y19 -> K=19 GEMM (stats) -> GEMM2 (BN from raw stats)
    k_agg_small<<<NB_AGG16, 256, 0, stream>>>((const uint4*)x0bf, rp, srcs, y19f);
    k_gemm_small<K0><<<NB_G32, 256, 0, stream>>>(y19f, w1_0, b1_0, hbf, gstat);
    k_gemm_bn<<<NB_G64, 256, 0, stream>>>(hbf, wt, b2_0, gstat, gm_0, bt_0, (unsigned short*)xbf);

    // layers 1..2: grouped agg (4 nodes/wave) + MFMA GEMM with atomic stats
    for (int i = 0; i < 2; ++i) {
        float* gs = gstat + (size_t)(1 + i) * STSLOT * 256;
        k_agg128_bf<<<NB_AGG4, 256, 0, stream>>>((const uint4*)xbf, rp, srcs, (uint4*)ybf);
        k_gemm_s1<<<NB_G64, 256, 0, stream>>>((const unsigned short*)ybf,
                wt + (size_t)(1 + i) * HH * HH, b1_r + i * HH, hbf, gs);
        k_gemm_bn<<<NB_G64, 256, 0, stream>>>(hbf, wt + (size_t)(3 + i) * HH * HH, b2_r + i * HH,
                                              gs, gm_r + i * HH, bt_r + i * HH, (unsigned short*)xbf);
    }

    // pooling + classifier
    k_pool_part<<<BB * PCH, 128, 0, stream>>>((const unsigned short*)xbf, gptr, psum, pmax);
    k_pool_cls1<<<BB, 128, 0, stream>>>(psum, pmax, gptr, g0, cw1, cb1, z1b);
    k_cls2<<<1, 128, 0, stream>>>(z1b, cgm, cbt, cw2, cb2, outp);
}